// Round 5
// baseline (3578.649 us; speedup 1.0000x reference)
//
#include <hip/hip_runtime.h>

// MACE node message block, f32. CSR-gather, channel-major tpw (coalesced stores).
// N=10000 nodes, E=160000 edges, C=128, RB=8, HID=64.
//
// ws layout (float units from base):
//   [0 .. 1.28M)            s_up   (N,128)
//   [1.28M .. 5.12M)        v_up   (N,128,3)
//   [5.12M .. 15.36M)       msg    (N,1024); cnt/cursor ints live here pre-gather
//   [15.36M .. 15.392768M)  W4t
//   [15392768 .. +10001]    row    (int)
//   [15402772 .. +160000]   elist  (int)
//   [15562772 .. )          tpw    chunk buffer, layout [c][chunkE] float4
// mandatory: 62.25 MB; tpw full-E adds +327.7 MB (chunked if ws smaller)

#define N_NODES 10000
#define N_EDGES 160000

#define S_UP_OFF   0u
#define V_UP_OFF   1280000u
#define MSG_OFF    5120000u
#define W4T_OFF    15360000u
#define ROW_OFF    15392768u
#define ELIST_OFF  15402772u
#define TPW_OFF    15562772u

__device__ __forceinline__ float silu(float x) {
    return x / (1.0f + __expf(-x));
}

constexpr float INV_SQRT_C  = 0.08838834764831845f;
constexpr float INV_SQRT_RB = 0.35355339059327373f;
constexpr float INV_SQRT_H  = 0.125f;
constexpr float OUT_SCALE   = 0.0625f * 0.0625f;      // 1/sqrt(256) / AVG_NEIGH
constexpr float C000 = 0.7071067811865476f;
constexpr float C110 = 0.4082482904638631f;
constexpr float C011 = 0.7071067811865476f;
constexpr float C101 = 0.7071067811865476f;

// ---------------- K0: transpose + prescale W_mlp4 ----------------
__global__ void k_w4t(const float* __restrict__ W4, float* __restrict__ W4t) {
    int o = blockIdx.x * 256 + threadIdx.x;   // 32768 total
    int c = o >> 8;
    int a = (o >> 6) & 3;
    int k = o & 63;
    W4t[o] = W4[k * 512 + a * 128 + c] * INV_SQRT_H;
}

// ---------------- K1: node up-projection ----------------
#define NPB 8
__global__ void k_node_up(const float* __restrict__ nf,
                          const float* __restrict__ Wus,
                          const float* __restrict__ Wuv,
                          float* __restrict__ s_up,
                          float* __restrict__ v_up) {
    __shared__ float lds[NPB][512];
    const int n0 = blockIdx.x * NPB;
    const int tid = threadIdx.x;  // 128 threads

    const float4* src = (const float4*)(nf + (size_t)n0 * 512);
    float4* dst = (float4*)(&lds[0][0]);
    #pragma unroll
    for (int i = 0; i < NPB; ++i) dst[tid + 128 * i] = src[tid + 128 * i];
    __syncthreads();

    const int d = tid;
    float acc_s[NPB];
    float acc_v[NPB][3];
    #pragma unroll
    for (int p = 0; p < NPB; ++p) {
        acc_s[p] = 0.f; acc_v[p][0] = 0.f; acc_v[p][1] = 0.f; acc_v[p][2] = 0.f;
    }
    for (int c = 0; c < 128; ++c) {
        float ws = Wus[c * 128 + d];
        float wv = Wuv[c * 128 + d];
        #pragma unroll
        for (int p = 0; p < NPB; ++p) {
            acc_s[p]    = fmaf(lds[p][c],             ws, acc_s[p]);
            acc_v[p][0] = fmaf(lds[p][128 + 3*c + 0], wv, acc_v[p][0]);
            acc_v[p][1] = fmaf(lds[p][128 + 3*c + 1], wv, acc_v[p][1]);
            acc_v[p][2] = fmaf(lds[p][128 + 3*c + 2], wv, acc_v[p][2]);
        }
    }
    #pragma unroll
    for (int p = 0; p < NPB; ++p) {
        int n = n0 + p;
        s_up[(size_t)n * 128 + d]         = acc_s[p]    * INV_SQRT_C;
        v_up[(size_t)n * 384 + 3*d + 0]   = acc_v[p][0] * INV_SQRT_C;
        v_up[(size_t)n * 384 + 3*d + 1]   = acc_v[p][1] * INV_SQRT_C;
        v_up[(size_t)n * 384 + 3*d + 2]   = acc_v[p][2] * INV_SQRT_C;
    }
}

// ---------------- CSR build ----------------
__global__ void k_hist(const int* __restrict__ ei, int* __restrict__ cnt) {
    int e = blockIdx.x * 256 + threadIdx.x;
    if (e < N_EDGES) atomicAdd(&cnt[ei[N_EDGES + e]], 1);
}

// single block, 256 threads, each covers 40 nodes
__global__ void k_scan(const int* __restrict__ cnt, int* __restrict__ row,
                       int* __restrict__ cursor) {
    __shared__ int part[256];
    const int t = threadIdx.x;
    const int base = t * 40;
    int s = 0;
    for (int i = 0; i < 40; ++i) {
        int idx = base + i;
        s += (idx < N_NODES) ? cnt[idx] : 0;
    }
    part[t] = s;
    __syncthreads();
    for (int off = 1; off < 256; off <<= 1) {
        int v = (t >= off) ? part[t - off] : 0;
        __syncthreads();
        part[t] += v;
        __syncthreads();
    }
    int run = part[t] - s;   // exclusive prefix
    for (int i = 0; i < 40; ++i) {
        int idx = base + i;
        if (idx < N_NODES) {
            row[idx] = run;
            cursor[idx] = run;
            run += cnt[idx];
        }
    }
    if (t == 255) row[N_NODES] = part[255];
}

__global__ void k_scatter(const int* __restrict__ ei, int* __restrict__ cursor,
                          int* __restrict__ elist) {
    int e = blockIdx.x * 256 + threadIdx.x;
    if (e < N_EDGES) {
        int r = ei[N_EDGES + e];
        int pos = atomicAdd(&cursor[r], 1);
        elist[pos] = e;
    }
}

// ---------------- K2: per-edge MLP -> tpw[c][i] (channel-major) ----------------
__global__ __launch_bounds__(256) void k_edge_mlp(
    const float* __restrict__ edge_feats,
    const float* __restrict__ W1,
    const float* __restrict__ W2,
    const float* __restrict__ W3,
    const float* __restrict__ W4t,
    const int*   __restrict__ elist,
    int c0, int ne, int chunkE,
    float4*      __restrict__ tpwv) {
    const int i = blockIdx.x * 256 + threadIdx.x;
    if (i >= ne) return;
    const int e = elist[c0 + i];

    float4 ef0 = ((const float4*)edge_feats)[e * 2 + 0];
    float4 ef1 = ((const float4*)edge_feats)[e * 2 + 1];
    float ef[8] = {ef0.x, ef0.y, ef0.z, ef0.w, ef1.x, ef1.y, ef1.z, ef1.w};

    // layer 1: 8 -> 64
    float h1[64];
    #pragma unroll
    for (int j = 0; j < 64; ++j) {
        float a0 = 0.f;
        #pragma unroll
        for (int k = 0; k < 8; ++k) a0 = fmaf(ef[k], W1[k * 64 + j], a0);
        h1[j] = silu(a0 * INV_SQRT_RB);
    }
    // layer 2: 64 -> 64
    float h2[64];
    #pragma unroll
    for (int j = 0; j < 64; ++j) h2[j] = 0.f;
    #pragma unroll
    for (int k = 0; k < 64; ++k) {
        float hk = h1[k];
        #pragma unroll
        for (int j = 0; j < 64; ++j) h2[j] = fmaf(hk, W2[k * 64 + j], h2[j]);
    }
    #pragma unroll
    for (int j = 0; j < 64; ++j) h2[j] = silu(h2[j] * INV_SQRT_H);
    // layer 3: 64 -> 64
    float h3[64];
    #pragma unroll
    for (int j = 0; j < 64; ++j) h3[j] = 0.f;
    #pragma unroll
    for (int k = 0; k < 64; ++k) {
        float hk = h2[k];
        #pragma unroll
        for (int j = 0; j < 64; ++j) h3[j] = fmaf(hk, W3[k * 64 + j], h3[j]);
    }
    #pragma unroll
    for (int j = 0; j < 64; ++j) h3[j] = silu(h3[j] * INV_SQRT_H);

    // layer 4: per channel c, 4 dots of 64; store float4 channel-major:
    // lanes i,i+1 write consecutive float4s -> fully coalesced wave stores.
    for (int c = 0; c < 128; ++c) {
        const float* w4c = W4t + c * 256;   // wave-uniform -> scalar loads
        float t0 = 0.f, t1 = 0.f, t2 = 0.f, t3 = 0.f;
        #pragma unroll
        for (int k = 0; k < 64; ++k) {
            float hk = h3[k];
            t0 = fmaf(hk, w4c[k],       t0);
            t1 = fmaf(hk, w4c[64 + k],  t1);
            t2 = fmaf(hk, w4c[128 + k], t2);
            t3 = fmaf(hk, w4c[192 + k], t3);
        }
        tpwv[(size_t)c * chunkE + i] = make_float4(t0, t1, t2, t3);
    }
}

// ---------------- K3: CSR gather per node (chunk-clipped) --------
// accum==0: overwrite msg (also writes zeros for nodes with no edges in chunk)
// accum==1: msg +=
__global__ __launch_bounds__(128) void k_gather(
    const int*    __restrict__ elist,
    const int*    __restrict__ row,
    const int*    __restrict__ ei,          // senders in ei[0..E)
    const float*  __restrict__ edge_attrs,
    const float4* __restrict__ tpwv,
    const float*  __restrict__ s_up,
    const float*  __restrict__ v_up,
    float*        __restrict__ msg,
    int c0, int c1, int chunkE, int accum) {
    const int nidx = blockIdx.x;
    const int c = threadIdx.x;      // 128 threads, one channel each
    int beg = row[nidx];
    int end = row[nidx + 1];
    if (beg < c0) beg = c0;
    if (end > c1) end = c1;
    if (accum && beg >= end) return;

    float a0 = 0.f, a1 = 0.f, a2 = 0.f, a3 = 0.f,
          a4 = 0.f, a5 = 0.f, a6 = 0.f, a7 = 0.f;

    for (int i = beg; i < end; ++i) {
        const int e   = elist[i];
        const int snd = ei[e];
        const float4 ea = ((const float4*)edge_attrs)[e];
        const float y0 = ea.x, y10 = ea.y, y11 = ea.z, y12 = ea.w;

        const float4 t = tpwv[(size_t)c * chunkE + (i - c0)];
        const float se  = s_up[(size_t)snd * 128 + c];
        const float ve0 = v_up[(size_t)snd * 384 + 3 * c + 0];
        const float ve1 = v_up[(size_t)snd * 384 + 3 * c + 1];
        const float ve2 = v_up[(size_t)snd * 384 + 3 * c + 2];

        a0 = fmaf(C000 * t.x * y0, se, a0);
        const float dvy = ve0 * y10 + ve1 * y11 + ve2 * y12;
        a1 = fmaf(C110 * t.w, dvy, a1);
        const float c011t = C011 * t.y * se;
        a2 = fmaf(c011t, y10, a2);
        a3 = fmaf(c011t, y11, a3);
        a4 = fmaf(c011t, y12, a4);
        const float c101t = C101 * t.z * y0;
        a5 = fmaf(c101t, ve0, a5);
        a6 = fmaf(c101t, ve1, a6);
        a7 = fmaf(c101t, ve2, a7);
    }

    float* m = msg + (size_t)nidx * 1024;
    if (accum) {
        m[c]               += a0;
        m[128 + c]         += a1;
        m[256 + 3 * c + 0] += a2;
        m[256 + 3 * c + 1] += a3;
        m[256 + 3 * c + 2] += a4;
        m[640 + 3 * c + 0] += a5;
        m[640 + 3 * c + 1] += a6;
        m[640 + 3 * c + 2] += a7;
    } else {
        m[c]               = a0;
        m[128 + c]         = a1;
        m[256 + 3 * c + 0] = a2;
        m[256 + 3 * c + 1] = a3;
        m[256 + 3 * c + 2] = a4;
        m[640 + 3 * c + 0] = a5;
        m[640 + 3 * c + 1] = a6;
        m[640 + 3 * c + 2] = a7;
    }
}

// ---------------- K4: final node linear ----------------
#define NPB3 8
__global__ void k_node_out(const float* __restrict__ msg,
                           const float* __restrict__ Wls,
                           const float* __restrict__ Wlv,
                           float* __restrict__ out) {
    __shared__ float lds[NPB3][1024];
    const int n0 = blockIdx.x * NPB3;
    const int tid = threadIdx.x;  // 128 threads

    const float4* src = (const float4*)(msg + (size_t)n0 * 1024);
    float4* dst = (float4*)(&lds[0][0]);
    #pragma unroll
    for (int i = 0; i < 2 * NPB3; ++i) dst[tid + 128 * i] = src[tid + 128 * i];
    __syncthreads();

    const int d = tid;
    float acc_s[NPB3];
    float acc_v[NPB3][3];
    #pragma unroll
    for (int p = 0; p < NPB3; ++p) {
        acc_s[p] = 0.f; acc_v[p][0] = 0.f; acc_v[p][1] = 0.f; acc_v[p][2] = 0.f;
    }
    for (int c = 0; c < 256; ++c) {
        float wls = Wls[c * 128 + d];
        float wlv = Wlv[c * 128 + d];
        #pragma unroll
        for (int p = 0; p < NPB3; ++p) {
            acc_s[p]    = fmaf(lds[p][c],               wls, acc_s[p]);
            acc_v[p][0] = fmaf(lds[p][256 + 3*c + 0],   wlv, acc_v[p][0]);
            acc_v[p][1] = fmaf(lds[p][256 + 3*c + 1],   wlv, acc_v[p][1]);
            acc_v[p][2] = fmaf(lds[p][256 + 3*c + 2],   wlv, acc_v[p][2]);
        }
    }
    #pragma unroll
    for (int p = 0; p < NPB3; ++p) {
        int n = n0 + p;
        out[(size_t)n * 512 + d]             = acc_s[p]    * OUT_SCALE;
        out[(size_t)n * 512 + 128 + 3*d + 0] = acc_v[p][0] * OUT_SCALE;
        out[(size_t)n * 512 + 128 + 3*d + 1] = acc_v[p][1] * OUT_SCALE;
        out[(size_t)n * 512 + 128 + 3*d + 2] = acc_v[p][2] * OUT_SCALE;
    }
}

extern "C" void kernel_launch(void* const* d_in, const int* in_sizes, int n_in,
                              void* d_out, int out_size, void* d_ws, size_t ws_size,
                              hipStream_t stream) {
    const float* node_feats = (const float*)d_in[1];
    const float* edge_attrs = (const float*)d_in[2];
    const float* edge_feats = (const float*)d_in[3];
    const int*   edge_index = (const int*)d_in[4];
    const float* W_up_s = (const float*)d_in[5];
    const float* W_up_v = (const float*)d_in[6];
    const float* W_mlp1 = (const float*)d_in[7];
    const float* W_mlp2 = (const float*)d_in[8];
    const float* W_mlp3 = (const float*)d_in[9];
    const float* W_mlp4 = (const float*)d_in[10];
    const float* W_lin_s = (const float*)d_in[11];
    const float* W_lin_v = (const float*)d_in[12];

    float* ws     = (float*)d_ws;
    float* s_up   = ws + S_UP_OFF;
    float* v_up   = ws + V_UP_OFF;
    float* msg    = ws + MSG_OFF;
    float* W4t    = ws + W4T_OFF;
    int*   row    = (int*)(ws + ROW_OFF);
    int*   elist  = (int*)(ws + ELIST_OFF);
    float4* tpwv  = (float4*)(ws + TPW_OFF);
    // cnt/cursor live inside the msg region until the gather overwrites it
    int*   cnt    = (int*)msg;
    int*   cursor = cnt + N_NODES;
    float* out_f  = (float*)d_out;

    // adaptive chunking: tpw capacity from actual ws_size (deterministic)
    size_t total_f = ws_size / 4;
    size_t cap_f   = (total_f > TPW_OFF) ? (total_f - TPW_OFF) : 0;
    int chunkE = (int)((cap_f / 512 < (size_t)N_EDGES) ? cap_f / 512 : (size_t)N_EDGES);
    if (chunkE < 1) chunkE = 1;
    const int nch = (N_EDGES + chunkE - 1) / chunkE;

    (void)hipMemsetAsync(cnt, 0, N_NODES * sizeof(int), stream);
    k_w4t<<<128, 256, 0, stream>>>(W_mlp4, W4t);
    k_node_up<<<N_NODES / NPB, 128, 0, stream>>>(node_feats, W_up_s, W_up_v, s_up, v_up);
    k_hist<<<N_EDGES / 256, 256, 0, stream>>>(edge_index, cnt);
    k_scan<<<1, 256, 0, stream>>>(cnt, row, cursor);
    k_scatter<<<N_EDGES / 256, 256, 0, stream>>>(edge_index, cursor, elist);

    for (int ch = 0; ch < nch; ++ch) {
        const int c0 = ch * chunkE;
        const int c1 = (c0 + chunkE < N_EDGES) ? c0 + chunkE : N_EDGES;
        const int ne = c1 - c0;
        k_edge_mlp<<<(ne + 255) / 256, 256, 0, stream>>>(
            edge_feats, W_mlp1, W_mlp2, W_mlp3, W4t, elist, c0, ne, chunkE, tpwv);
        k_gather<<<N_NODES, 128, 0, stream>>>(
            elist, row, edge_index, edge_attrs, tpwv, s_up, v_up, msg,
            c0, c1, chunkE, ch == 0 ? 0 : 1);
    }
    k_node_out<<<N_NODES / NPB3, 128, 0, stream>>>(msg, W_lin_s, W_lin_v, out_f);
}

// Round 6
// 1239.624 us; speedup vs baseline: 2.8869x; 2.8869x over previous
//
#include <hip/hip_runtime.h>

// MACE node message block, f32. LDS-tiled fused edge MLP + CSR gather.
// N=10000 nodes, E=160000 edges, C=128, RB=8, HID=64.
//
// ws layout (float units from base):
//   [0 .. 1.28M)            s_up   (N,128)
//   [1.28M .. 5.12M)        v_up   (N,128,3)
//   [5.12M .. 15.36M)       msg    (N,1024); cnt/cursor ints live here pre-gather
//   [15.36M .. 15.392768M)  W4b    (k-major transposed/prescaled W_mlp4)
//   [15392768 .. +10001]    row    (int)
//   [15402772 .. +160000]   elist  (int)
//   [15562772 .. )          tpw    chunk buffer, [pos][c] float4 (edge-major)
// full-E total: 97,482,772 floats = 389.9 MB (same as proven R5 footprint)

#define N_NODES 10000
#define N_EDGES 160000

#define S_UP_OFF   0u
#define V_UP_OFF   1280000u
#define MSG_OFF    5120000u
#define W4B_OFF    15360000u
#define ROW_OFF    15392768u
#define ELIST_OFF  15402772u
#define TPW_OFF    15562772u

__device__ __forceinline__ float silu(float x) {
    return x / (1.0f + __expf(-x));
}

constexpr float INV_SQRT_C  = 0.08838834764831845f;
constexpr float INV_SQRT_RB = 0.35355339059327373f;
constexpr float INV_SQRT_H  = 0.125f;
constexpr float OUT_SCALE   = 0.0625f * 0.0625f;      // 1/sqrt(256) / AVG_NEIGH
constexpr float C000 = 0.7071067811865476f;
constexpr float C110 = 0.4082482904638631f;
constexpr float C011 = 0.7071067811865476f;
constexpr float C101 = 0.7071067811865476f;

// ---------------- K0: repack + prescale W_mlp4 ----------------
// W4b[k*512 + c*4 + a] = W4[k*512 + a*128 + c] / sqrt(64)
// -> per (k, wave) the 32 consecutive weights are wave-uniform contiguous.
__global__ void k_w4t(const float* __restrict__ W4, float* __restrict__ W4b) {
    int o = blockIdx.x * 256 + threadIdx.x;   // 32768 total
    int k = o >> 9;
    int r = o & 511;
    int c = r >> 2;
    int a = r & 3;
    W4b[o] = W4[k * 512 + a * 128 + c] * INV_SQRT_H;
}

// ---------------- K1: node up-projection ----------------
#define NPB 8
__global__ void k_node_up(const float* __restrict__ nf,
                          const float* __restrict__ Wus,
                          const float* __restrict__ Wuv,
                          float* __restrict__ s_up,
                          float* __restrict__ v_up) {
    __shared__ float lds[NPB][512];
    const int n0 = blockIdx.x * NPB;
    const int tid = threadIdx.x;  // 128 threads

    const float4* src = (const float4*)(nf + (size_t)n0 * 512);
    float4* dst = (float4*)(&lds[0][0]);
    #pragma unroll
    for (int i = 0; i < NPB; ++i) dst[tid + 128 * i] = src[tid + 128 * i];
    __syncthreads();

    const int d = tid;
    float acc_s[NPB];
    float acc_v[NPB][3];
    #pragma unroll
    for (int p = 0; p < NPB; ++p) {
        acc_s[p] = 0.f; acc_v[p][0] = 0.f; acc_v[p][1] = 0.f; acc_v[p][2] = 0.f;
    }
    for (int c = 0; c < 128; ++c) {
        float ws = Wus[c * 128 + d];
        float wv = Wuv[c * 128 + d];
        #pragma unroll
        for (int p = 0; p < NPB; ++p) {
            acc_s[p]    = fmaf(lds[p][c],             ws, acc_s[p]);
            acc_v[p][0] = fmaf(lds[p][128 + 3*c + 0], wv, acc_v[p][0]);
            acc_v[p][1] = fmaf(lds[p][128 + 3*c + 1], wv, acc_v[p][1]);
            acc_v[p][2] = fmaf(lds[p][128 + 3*c + 2], wv, acc_v[p][2]);
        }
    }
    #pragma unroll
    for (int p = 0; p < NPB; ++p) {
        int n = n0 + p;
        s_up[(size_t)n * 128 + d]         = acc_s[p]    * INV_SQRT_C;
        v_up[(size_t)n * 384 + 3*d + 0]   = acc_v[p][0] * INV_SQRT_C;
        v_up[(size_t)n * 384 + 3*d + 1]   = acc_v[p][1] * INV_SQRT_C;
        v_up[(size_t)n * 384 + 3*d + 2]   = acc_v[p][2] * INV_SQRT_C;
    }
}

// ---------------- CSR build ----------------
__global__ void k_hist(const int* __restrict__ ei, int* __restrict__ cnt) {
    int e = blockIdx.x * 256 + threadIdx.x;
    if (e < N_EDGES) atomicAdd(&cnt[ei[N_EDGES + e]], 1);
}

__global__ void k_scan(const int* __restrict__ cnt, int* __restrict__ row,
                       int* __restrict__ cursor) {
    __shared__ int part[256];
    const int t = threadIdx.x;
    const int base = t * 40;
    int s = 0;
    for (int i = 0; i < 40; ++i) {
        int idx = base + i;
        s += (idx < N_NODES) ? cnt[idx] : 0;
    }
    part[t] = s;
    __syncthreads();
    for (int off = 1; off < 256; off <<= 1) {
        int v = (t >= off) ? part[t - off] : 0;
        __syncthreads();
        part[t] += v;
        __syncthreads();
    }
    int run = part[t] - s;   // exclusive prefix
    for (int i = 0; i < 40; ++i) {
        int idx = base + i;
        if (idx < N_NODES) {
            row[idx] = run;
            cursor[idx] = run;
            run += cnt[idx];
        }
    }
    if (t == 255) row[N_NODES] = part[255];
}

__global__ void k_scatter(const int* __restrict__ ei, int* __restrict__ cursor,
                          int* __restrict__ elist) {
    int e = blockIdx.x * 256 + threadIdx.x;
    if (e < N_EDGES) {
        int r = ei[N_EDGES + e];
        int pos = atomicAdd(&cursor[r], 1);
        elist[pos] = e;
    }
}

// ---------------- K2: fused LDS-tiled edge MLP -> tpw[pos][c] float4 -------
// Block: 256 threads = 64 edges (el = tid&63) x 4 j-groups (g = tid>>6).
// Activations in LDS [hid][edge] (lanes read consecutive edges: conflict-free).
// Weight reads are wave-uniform -> scalar loads.
__global__ __launch_bounds__(256) void k_edge_fused(
    const float* __restrict__ edge_feats,
    const float* __restrict__ W1,
    const float* __restrict__ W2,
    const float* __restrict__ W3,
    const float* __restrict__ W4b,
    const int*   __restrict__ elist,
    int c0, int ne,
    float4*      __restrict__ tpwv) {
    __shared__ float hA[64][64];
    __shared__ float hB[64][64];   // rows 0..7 double as the ef staging buffer

    const int tid = threadIdx.x;
    const int el  = tid & 63;
    const int g   = tid >> 6;            // wave index; uniform within wave
    const int i   = blockIdx.x * 64 + el;
    const bool valid = (i < ne);
    const int e = elist[c0 + (valid ? i : 0)];

    // stage edge_feats transposed into hB[0..7][el]
    if (g < 2) {
        float4 f = ((const float4*)edge_feats)[(size_t)e * 2 + g];
        hB[g * 4 + 0][el] = f.x;
        hB[g * 4 + 1][el] = f.y;
        hB[g * 4 + 2][el] = f.z;
        hB[g * 4 + 3][el] = f.w;
    }
    __syncthreads();

    // ---- layer 1: 8 -> 64, thread owns j = g*16 .. g*16+15
    {
        float acc[16];
        #pragma unroll
        for (int jj = 0; jj < 16; ++jj) acc[jj] = 0.f;
        #pragma unroll
        for (int k = 0; k < 8; ++k) {
            const float hk = hB[k][el];
            const float* w = W1 + k * 64 + g * 16;
            #pragma unroll
            for (int jj = 0; jj < 16; ++jj) acc[jj] = fmaf(hk, w[jj], acc[jj]);
        }
        #pragma unroll
        for (int jj = 0; jj < 16; ++jj)
            hA[g * 16 + jj][el] = silu(acc[jj] * INV_SQRT_RB);
    }
    __syncthreads();

    // ---- layer 2: 64 -> 64 (read hA, write hB)
    {
        float acc[16];
        #pragma unroll
        for (int jj = 0; jj < 16; ++jj) acc[jj] = 0.f;
        for (int k = 0; k < 64; ++k) {
            const float hk = hA[k][el];
            const float* w = W2 + k * 64 + g * 16;
            #pragma unroll
            for (int jj = 0; jj < 16; ++jj) acc[jj] = fmaf(hk, w[jj], acc[jj]);
        }
        __syncthreads();   // everyone done reading hA... (hB rows 0..7 still live as ef? no: dead)
        #pragma unroll
        for (int jj = 0; jj < 16; ++jj)
            hB[g * 16 + jj][el] = silu(acc[jj] * INV_SQRT_H);
    }
    __syncthreads();

    // ---- layer 3: 64 -> 64 (read hB, write hA)
    {
        float acc[16];
        #pragma unroll
        for (int jj = 0; jj < 16; ++jj) acc[jj] = 0.f;
        for (int k = 0; k < 64; ++k) {
            const float hk = hB[k][el];
            const float* w = W3 + k * 64 + g * 16;
            #pragma unroll
            for (int jj = 0; jj < 16; ++jj) acc[jj] = fmaf(hk, w[jj], acc[jj]);
        }
        __syncthreads();
        #pragma unroll
        for (int jj = 0; jj < 16; ++jj)
            hA[g * 16 + jj][el] = silu(acc[jj] * INV_SQRT_H);
    }
    __syncthreads();

    // ---- layer 4: 64 -> 512, thread covers outputs o = g*128 + p*32 + q
    // o maps to (c = o>>2, a = o&3); W4b is o-contiguous per k.
    for (int p = 0; p < 4; ++p) {
        float a4[32];
        #pragma unroll
        for (int q = 0; q < 32; ++q) a4[q] = 0.f;
        for (int k = 0; k < 64; ++k) {
            const float hk = hA[k][el];
            const float* w = W4b + (k << 9) + (g << 7) + (p << 5);
            #pragma unroll
            for (int q = 0; q < 32; ++q) a4[q] = fmaf(hk, w[q], a4[q]);
        }
        if (valid) {
            float4* tp = tpwv + (size_t)i * 128 + g * 32 + p * 8;
            #pragma unroll
            for (int cl = 0; cl < 8; ++cl)
                tp[cl] = make_float4(a4[cl*4+0], a4[cl*4+1], a4[cl*4+2], a4[cl*4+3]);
        }
    }
}

// ---------------- K3: CSR gather per node (chunk-clipped) --------
// accum==0: overwrite msg; accum==1: msg +=
__global__ __launch_bounds__(128) void k_gather(
    const int*    __restrict__ elist,
    const int*    __restrict__ row,
    const int*    __restrict__ ei,          // senders in ei[0..E)
    const float*  __restrict__ edge_attrs,
    const float4* __restrict__ tpwv,
    const float*  __restrict__ s_up,
    const float*  __restrict__ v_up,
    float*        __restrict__ msg,
    int c0, int c1, int accum) {
    const int nidx = blockIdx.x;
    const int c = threadIdx.x;      // 128 threads, one channel each
    int beg = row[nidx];
    int end = row[nidx + 1];
    if (beg < c0) beg = c0;
    if (end > c1) end = c1;
    if (accum && beg >= end) return;

    float a0 = 0.f, a1 = 0.f, a2 = 0.f, a3 = 0.f,
          a4 = 0.f, a5 = 0.f, a6 = 0.f, a7 = 0.f;

    for (int i = beg; i < end; ++i) {
        const int e   = elist[i];
        const int snd = ei[e];
        const float4 ea = ((const float4*)edge_attrs)[e];
        const float y0 = ea.x, y10 = ea.y, y11 = ea.z, y12 = ea.w;

        const float4 t = tpwv[(size_t)(i - c0) * 128 + c];
        const float se  = s_up[(size_t)snd * 128 + c];
        const float ve0 = v_up[(size_t)snd * 384 + 3 * c + 0];
        const float ve1 = v_up[(size_t)snd * 384 + 3 * c + 1];
        const float ve2 = v_up[(size_t)snd * 384 + 3 * c + 2];

        a0 = fmaf(C000 * t.x * y0, se, a0);
        const float dvy = ve0 * y10 + ve1 * y11 + ve2 * y12;
        a1 = fmaf(C110 * t.w, dvy, a1);
        const float c011t = C011 * t.y * se;
        a2 = fmaf(c011t, y10, a2);
        a3 = fmaf(c011t, y11, a3);
        a4 = fmaf(c011t, y12, a4);
        const float c101t = C101 * t.z * y0;
        a5 = fmaf(c101t, ve0, a5);
        a6 = fmaf(c101t, ve1, a6);
        a7 = fmaf(c101t, ve2, a7);
    }

    float* m = msg + (size_t)nidx * 1024;
    if (accum) {
        m[c]               += a0;
        m[128 + c]         += a1;
        m[256 + 3 * c + 0] += a2;
        m[256 + 3 * c + 1] += a3;
        m[256 + 3 * c + 2] += a4;
        m[640 + 3 * c + 0] += a5;
        m[640 + 3 * c + 1] += a6;
        m[640 + 3 * c + 2] += a7;
    } else {
        m[c]               = a0;
        m[128 + c]         = a1;
        m[256 + 3 * c + 0] = a2;
        m[256 + 3 * c + 1] = a3;
        m[256 + 3 * c + 2] = a4;
        m[640 + 3 * c + 0] = a5;
        m[640 + 3 * c + 1] = a6;
        m[640 + 3 * c + 2] = a7;
    }
}

// ---------------- K4: final node linear ----------------
#define NPB3 8
__global__ void k_node_out(const float* __restrict__ msg,
                           const float* __restrict__ Wls,
                           const float* __restrict__ Wlv,
                           float* __restrict__ out) {
    __shared__ float lds[NPB3][1024];
    const int n0 = blockIdx.x * NPB3;
    const int tid = threadIdx.x;  // 128 threads

    const float4* src = (const float4*)(msg + (size_t)n0 * 1024);
    float4* dst = (float4*)(&lds[0][0]);
    #pragma unroll
    for (int i = 0; i < 2 * NPB3; ++i) dst[tid + 128 * i] = src[tid + 128 * i];
    __syncthreads();

    const int d = tid;
    float acc_s[NPB3];
    float acc_v[NPB3][3];
    #pragma unroll
    for (int p = 0; p < NPB3; ++p) {
        acc_s[p] = 0.f; acc_v[p][0] = 0.f; acc_v[p][1] = 0.f; acc_v[p][2] = 0.f;
    }
    for (int c = 0; c < 256; ++c) {
        float wls = Wls[c * 128 + d];
        float wlv = Wlv[c * 128 + d];
        #pragma unroll
        for (int p = 0; p < NPB3; ++p) {
            acc_s[p]    = fmaf(lds[p][c],               wls, acc_s[p]);
            acc_v[p][0] = fmaf(lds[p][256 + 3*c + 0],   wlv, acc_v[p][0]);
            acc_v[p][1] = fmaf(lds[p][256 + 3*c + 1],   wlv, acc_v[p][1]);
            acc_v[p][2] = fmaf(lds[p][256 + 3*c + 2],   wlv, acc_v[p][2]);
        }
    }
    #pragma unroll
    for (int p = 0; p < NPB3; ++p) {
        int n = n0 + p;
        out[(size_t)n * 512 + d]             = acc_s[p]    * OUT_SCALE;
        out[(size_t)n * 512 + 128 + 3*d + 0] = acc_v[p][0] * OUT_SCALE;
        out[(size_t)n * 512 + 128 + 3*d + 1] = acc_v[p][1] * OUT_SCALE;
        out[(size_t)n * 512 + 128 + 3*d + 2] = acc_v[p][2] * OUT_SCALE;
    }
}

extern "C" void kernel_launch(void* const* d_in, const int* in_sizes, int n_in,
                              void* d_out, int out_size, void* d_ws, size_t ws_size,
                              hipStream_t stream) {
    const float* node_feats = (const float*)d_in[1];
    const float* edge_attrs = (const float*)d_in[2];
    const float* edge_feats = (const float*)d_in[3];
    const int*   edge_index = (const int*)d_in[4];
    const float* W_up_s = (const float*)d_in[5];
    const float* W_up_v = (const float*)d_in[6];
    const float* W_mlp1 = (const float*)d_in[7];
    const float* W_mlp2 = (const float*)d_in[8];
    const float* W_mlp3 = (const float*)d_in[9];
    const float* W_mlp4 = (const float*)d_in[10];
    const float* W_lin_s = (const float*)d_in[11];
    const float* W_lin_v = (const float*)d_in[12];

    float* ws     = (float*)d_ws;
    float* s_up   = ws + S_UP_OFF;
    float* v_up   = ws + V_UP_OFF;
    float* msg    = ws + MSG_OFF;
    float* W4b    = ws + W4B_OFF;
    int*   row    = (int*)(ws + ROW_OFF);
    int*   elist  = (int*)(ws + ELIST_OFF);
    float4* tpwv  = (float4*)(ws + TPW_OFF);
    // cnt/cursor live inside the msg region; gather overwrites it later
    int*   cnt    = (int*)msg;
    int*   cursor = cnt + N_NODES;
    float* out_f  = (float*)d_out;

    // adaptive chunking: tpw capacity from actual ws_size (deterministic)
    size_t total_f = ws_size / 4;
    size_t cap_f   = (total_f > TPW_OFF) ? (total_f - TPW_OFF) : 0;
    long long ce = (long long)(cap_f / 512);       // float4 slots per edge = 128 -> 512 floats
    ce &= ~63LL;                                   // multiple of block tile (64)
    if (ce < 64) ce = 64;
    if (ce > N_EDGES) ce = N_EDGES;
    const int chunkE = (int)ce;
    const int nch = (N_EDGES + chunkE - 1) / chunkE;

    (void)hipMemsetAsync(cnt, 0, 2 * N_NODES * sizeof(int), stream);
    k_w4t<<<128, 256, 0, stream>>>(W_mlp4, W4b);
    k_node_up<<<N_NODES / NPB, 128, 0, stream>>>(node_feats, W_up_s, W_up_v, s_up, v_up);
    k_hist<<<N_EDGES / 256, 256, 0, stream>>>(edge_index, cnt);
    k_scan<<<1, 256, 0, stream>>>(cnt, row, cursor);
    k_scatter<<<N_EDGES / 256, 256, 0, stream>>>(edge_index, cursor, elist);

    for (int ch = 0; ch < nch; ++ch) {
        const int c0 = ch * chunkE;
        const int c1 = (c0 + chunkE < N_EDGES) ? c0 + chunkE : N_EDGES;
        const int ne = c1 - c0;
        k_edge_fused<<<(ne + 63) / 64, 256, 0, stream>>>(
            edge_feats, W_mlp1, W_mlp2, W_mlp3, W4b, elist, c0, ne, tpwv);
        k_gather<<<N_NODES, 128, 0, stream>>>(
            elist, row, edge_index, edge_attrs, tpwv, s_up, v_up, msg,
            c0, c1, ch == 0 ? 0 : 1);
    }
    k_node_out<<<N_NODES / NPB3, 128, 0, stream>>>(msg, W_lin_s, W_lin_v, out_f);
}

// Round 7
// 478.915 us; speedup vs baseline: 7.4724x; 2.5884x over previous
//
#include <hip/hip_runtime.h>

// MACE node message block. bf16-MFMA edge MLP + CSR gather.
// N=10000, E=160000, C=128, RB=8, HID=64.
//
// ws layout (float units):
//   [0 .. 1.28M)        s_up (N,128)
//   [1.28M .. 5.12M)    v_up (N,128,3)
//   [5.12M .. 15.36M)   msg (N,1024); cnt/cursor ints live here pre-gather
//   [15.36M .. +20480)  W2p/W3p/W4p bf16 fragment-packed weights
//   [15380480 +10001]   row (int)
//   [15390484 +160000]  elist (int)
//   [15550484 +160000]  snds (int)   sender per sorted position
//   [15710484 +640000]  eas (float4) edge_attrs per sorted position
//   [16350484 .. )      tpw chunk buffer [pos][512] f32
// cap total at <= 97,482,772 floats (389.93 MB, proven to fit in R4-R6)

#define N_NODES 10000
#define N_EDGES 160000

#define S_UP_OFF   0u
#define V_UP_OFF   1280000u
#define MSG_OFF    5120000u
#define WP_OFF     15360000u
#define ROW_OFF    15380480u
#define ELIST_OFF  15390484u
#define SNDS_OFF   15550484u
#define EAS_OFF    15710484u
#define TPW_OFF    16350484u
#define MAX_TOTAL_F 97482772u

typedef __attribute__((ext_vector_type(8))) short bf16x8;
typedef __attribute__((ext_vector_type(4))) float f32x4;

__device__ __forceinline__ float silu(float x) {
    return x / (1.0f + __expf(-x));
}
__device__ __forceinline__ short f2bf(float x) {
    unsigned u = __float_as_uint(x);
    unsigned r = (u + 0x7FFFu + ((u >> 16) & 1u)) >> 16;
    return (short)r;
}

constexpr float INV_SQRT_C  = 0.08838834764831845f;
constexpr float INV_SQRT_RB = 0.35355339059327373f;
constexpr float INV_SQRT_H  = 0.125f;
constexpr float OUT_SCALE   = 0.0625f * 0.0625f;      // 1/sqrt(256) / AVG_NEIGH
constexpr float C000 = 0.7071067811865476f;
constexpr float C110 = 0.4082482904638631f;
constexpr float C011 = 0.7071067811865476f;
constexpr float C101 = 0.7071067811865476f;

// ---------------- K0: pack weights into bf16 MFMA B-fragment order ----------
// Frag order: [ntile][ktile][lane(64)][e(8)], value = W[k][col]*scale with
// k = ktile*32 + (lane>>4)*8 + e, col = ntile*16 + (lane&15).
__global__ void k_pack(const float* __restrict__ W2, const float* __restrict__ W3,
                       const float* __restrict__ W4,
                       short* __restrict__ W2p, short* __restrict__ W3p,
                       short* __restrict__ W4p) {
    int idx = blockIdx.x * 256 + threadIdx.x;   // 40960 total
    if (idx < 4096) {
        int i2 = idx;
        int e = i2 & 7, l = (i2 >> 3) & 63, kt = (i2 >> 9) & 1, nt = i2 >> 10;
        int k = kt * 32 + (l >> 4) * 8 + e;
        int col = nt * 16 + (l & 15);
        W2p[i2] = f2bf(W2[k * 64 + col] * INV_SQRT_H);
    } else if (idx < 8192) {
        int i2 = idx - 4096;
        int e = i2 & 7, l = (i2 >> 3) & 63, kt = (i2 >> 9) & 1, nt = i2 >> 10;
        int k = kt * 32 + (l >> 4) * 8 + e;
        int col = nt * 16 + (l & 15);
        W3p[i2] = f2bf(W3[k * 64 + col] * INV_SQRT_H);
    } else if (idx < 40960) {
        int i2 = idx - 8192;
        int e = i2 & 7, l = (i2 >> 3) & 63, kt = (i2 >> 9) & 1, nt = i2 >> 10; // nt 0..31
        int k = kt * 32 + (l >> 4) * 8 + e;
        int o = nt * 16 + (l & 15);      // o = c*4 + a
        int c = o >> 2, a = o & 3;
        W4p[i2] = f2bf(W4[k * 512 + a * 128 + c] * INV_SQRT_H);
    }
}

// ---------------- K1: node up-projection (f32, unchanged) ----------------
#define NPB 8
__global__ void k_node_up(const float* __restrict__ nf,
                          const float* __restrict__ Wus,
                          const float* __restrict__ Wuv,
                          float* __restrict__ s_up,
                          float* __restrict__ v_up) {
    __shared__ float lds[NPB][512];
    const int n0 = blockIdx.x * NPB;
    const int tid = threadIdx.x;  // 128 threads

    const float4* src = (const float4*)(nf + (size_t)n0 * 512);
    float4* dst = (float4*)(&lds[0][0]);
    #pragma unroll
    for (int i = 0; i < NPB; ++i) dst[tid + 128 * i] = src[tid + 128 * i];
    __syncthreads();

    const int d = tid;
    float acc_s[NPB];
    float acc_v[NPB][3];
    #pragma unroll
    for (int p = 0; p < NPB; ++p) {
        acc_s[p] = 0.f; acc_v[p][0] = 0.f; acc_v[p][1] = 0.f; acc_v[p][2] = 0.f;
    }
    for (int c = 0; c < 128; ++c) {
        float ws = Wus[c * 128 + d];
        float wv = Wuv[c * 128 + d];
        #pragma unroll
        for (int p = 0; p < NPB; ++p) {
            acc_s[p]    = fmaf(lds[p][c],             ws, acc_s[p]);
            acc_v[p][0] = fmaf(lds[p][128 + 3*c + 0], wv, acc_v[p][0]);
            acc_v[p][1] = fmaf(lds[p][128 + 3*c + 1], wv, acc_v[p][1]);
            acc_v[p][2] = fmaf(lds[p][128 + 3*c + 2], wv, acc_v[p][2]);
        }
    }
    #pragma unroll
    for (int p = 0; p < NPB; ++p) {
        int n = n0 + p;
        s_up[(size_t)n * 128 + d]         = acc_s[p]    * INV_SQRT_C;
        v_up[(size_t)n * 384 + 3*d + 0]   = acc_v[p][0] * INV_SQRT_C;
        v_up[(size_t)n * 384 + 3*d + 1]   = acc_v[p][1] * INV_SQRT_C;
        v_up[(size_t)n * 384 + 3*d + 2]   = acc_v[p][2] * INV_SQRT_C;
    }
}

// ---------------- CSR build ----------------
__global__ void k_hist(const int* __restrict__ ei, int* __restrict__ cnt) {
    int e = blockIdx.x * 256 + threadIdx.x;
    if (e < N_EDGES) atomicAdd(&cnt[ei[N_EDGES + e]], 1);
}

__global__ void k_scan(const int* __restrict__ cnt, int* __restrict__ row,
                       int* __restrict__ cursor) {
    __shared__ int part[256];
    const int t = threadIdx.x;
    const int base = t * 40;
    int s = 0;
    for (int i = 0; i < 40; ++i) {
        int idx = base + i;
        s += (idx < N_NODES) ? cnt[idx] : 0;
    }
    part[t] = s;
    __syncthreads();
    for (int off = 1; off < 256; off <<= 1) {
        int v = (t >= off) ? part[t - off] : 0;
        __syncthreads();
        part[t] += v;
        __syncthreads();
    }
    int run = part[t] - s;   // exclusive prefix
    for (int i = 0; i < 40; ++i) {
        int idx = base + i;
        if (idx < N_NODES) {
            row[idx] = run;
            cursor[idx] = run;
            run += cnt[idx];
        }
    }
    if (t == 255) row[N_NODES] = part[255];
}

__global__ void k_scatter(const int* __restrict__ ei, int* __restrict__ cursor,
                          const float* __restrict__ edge_attrs,
                          int* __restrict__ elist, int* __restrict__ snds,
                          float4* __restrict__ eas) {
    int e = blockIdx.x * 256 + threadIdx.x;
    if (e < N_EDGES) {
        int snd = ei[e];
        int r = ei[N_EDGES + e];
        int pos = atomicAdd(&cursor[r], 1);
        elist[pos] = e;
        snds[pos] = snd;
        eas[pos] = ((const float4*)edge_attrs)[e];
    }
}

// ---------------- K2: bf16-MFMA edge MLP -> tpw[pos][512] f32 ----------------
// Block = 64 sorted positions, 256 threads = 4 waves; wave w owns edges
// w*16..w*16+15 exclusively -> no barriers anywhere.
__global__ __launch_bounds__(256) void k_edge_mfma(
    const float* __restrict__ edge_feats,
    const float* __restrict__ W1,
    const short* __restrict__ W2p,
    const short* __restrict__ W3p,
    const short* __restrict__ W4p,
    const int*   __restrict__ elist,
    int c0, int ne,
    float*       __restrict__ tpw) {
    __shared__ __align__(16) short h0[64][72];   // padded: 2-way banks only
    __shared__ __align__(16) short h1[64][72];

    const int tid = threadIdx.x;
    const int l   = tid & 63;
    const int w   = tid >> 6;
    const int r16 = l & 15;
    const int g4  = l >> 4;
    const int base = blockIdx.x * 64;
    const int erow = w * 16 + r16;               // this lane's edge row

    // ---- layer 1 (f32 VALU): edge erow, outputs j0..j0+15
    {
        const int pos = base + erow;
        const int e = elist[c0 + ((pos < ne) ? pos : 0)];
        float4 f0 = ((const float4*)edge_feats)[(size_t)e * 2 + 0];
        float4 f1 = ((const float4*)edge_feats)[(size_t)e * 2 + 1];
        float ef[8] = {f0.x, f0.y, f0.z, f0.w, f1.x, f1.y, f1.z, f1.w};
        const int j0 = g4 * 16;
        float acc[16];
        #pragma unroll
        for (int jj = 0; jj < 16; ++jj) acc[jj] = 0.f;
        #pragma unroll
        for (int k = 0; k < 8; ++k) {
            const float* wr = W1 + k * 64 + j0;
            float4 w0 = *(const float4*)(wr + 0);
            float4 w1 = *(const float4*)(wr + 4);
            float4 w2 = *(const float4*)(wr + 8);
            float4 w3 = *(const float4*)(wr + 12);
            const float hk = ef[k];
            acc[0]  = fmaf(hk, w0.x, acc[0]);  acc[1]  = fmaf(hk, w0.y, acc[1]);
            acc[2]  = fmaf(hk, w0.z, acc[2]);  acc[3]  = fmaf(hk, w0.w, acc[3]);
            acc[4]  = fmaf(hk, w1.x, acc[4]);  acc[5]  = fmaf(hk, w1.y, acc[5]);
            acc[6]  = fmaf(hk, w1.z, acc[6]);  acc[7]  = fmaf(hk, w1.w, acc[7]);
            acc[8]  = fmaf(hk, w2.x, acc[8]);  acc[9]  = fmaf(hk, w2.y, acc[9]);
            acc[10] = fmaf(hk, w2.z, acc[10]); acc[11] = fmaf(hk, w2.w, acc[11]);
            acc[12] = fmaf(hk, w3.x, acc[12]); acc[13] = fmaf(hk, w3.y, acc[13]);
            acc[14] = fmaf(hk, w3.z, acc[14]); acc[15] = fmaf(hk, w3.w, acc[15]);
        }
        unsigned pk[8];
        #pragma unroll
        for (int q = 0; q < 8; ++q) {
            unsigned lo = (unsigned short)f2bf(silu(acc[2*q]     * INV_SQRT_RB));
            unsigned hi = (unsigned short)f2bf(silu(acc[2*q + 1] * INV_SQRT_RB));
            pk[q] = lo | (hi << 16);
        }
        uint4 A; A.x = pk[0]; A.y = pk[1]; A.z = pk[2]; A.w = pk[3];
        uint4 B; B.x = pk[4]; B.y = pk[5]; B.z = pk[6]; B.w = pk[7];
        *(uint4*)&h0[erow][j0]     = A;
        *(uint4*)&h0[erow][j0 + 8] = B;
    }

    // ---- layer 2: h0 -> h1  (MFMA 16x16x32 bf16, K=64 = 2 k-tiles)
    {
        bf16x8 a0 = *(const bf16x8*)&h0[erow][g4 * 8];
        bf16x8 a1 = *(const bf16x8*)&h0[erow][32 + g4 * 8];
        #pragma unroll
        for (int nt = 0; nt < 4; ++nt) {
            bf16x8 b0 = *(const bf16x8*)(W2p + ((nt * 2 + 0) * 64 + l) * 8);
            bf16x8 b1 = *(const bf16x8*)(W2p + ((nt * 2 + 1) * 64 + l) * 8);
            f32x4 c = {0.f, 0.f, 0.f, 0.f};
            c = __builtin_amdgcn_mfma_f32_16x16x32_bf16(a0, b0, c, 0, 0, 0);
            c = __builtin_amdgcn_mfma_f32_16x16x32_bf16(a1, b1, c, 0, 0, 0);
            #pragma unroll
            for (int r = 0; r < 4; ++r)
                h1[w * 16 + g4 * 4 + r][nt * 16 + r16] = f2bf(silu(c[r]));
        }
    }

    // ---- layer 3: h1 -> h0
    {
        bf16x8 a0 = *(const bf16x8*)&h1[erow][g4 * 8];
        bf16x8 a1 = *(const bf16x8*)&h1[erow][32 + g4 * 8];
        #pragma unroll
        for (int nt = 0; nt < 4; ++nt) {
            bf16x8 b0 = *(const bf16x8*)(W3p + ((nt * 2 + 0) * 64 + l) * 8);
            bf16x8 b1 = *(const bf16x8*)(W3p + ((nt * 2 + 1) * 64 + l) * 8);
            f32x4 c = {0.f, 0.f, 0.f, 0.f};
            c = __builtin_amdgcn_mfma_f32_16x16x32_bf16(a0, b0, c, 0, 0, 0);
            c = __builtin_amdgcn_mfma_f32_16x16x32_bf16(a1, b1, c, 0, 0, 0);
            #pragma unroll
            for (int r = 0; r < 4; ++r)
                h0[w * 16 + g4 * 4 + r][nt * 16 + r16] = f2bf(silu(c[r]));
        }
    }

    // ---- layer 4: h0 @ W4p -> tpw (32 n-tiles of 16 outputs)
    {
        bf16x8 a0 = *(const bf16x8*)&h0[erow][g4 * 8];
        bf16x8 a1 = *(const bf16x8*)&h0[erow][32 + g4 * 8];
        const int p0 = base + w * 16 + g4 * 4;
        #pragma unroll 2
        for (int nt = 0; nt < 32; ++nt) {
            bf16x8 b0 = *(const bf16x8*)(W4p + ((nt * 2 + 0) * 64 + l) * 8);
            bf16x8 b1 = *(const bf16x8*)(W4p + ((nt * 2 + 1) * 64 + l) * 8);
            f32x4 c = {0.f, 0.f, 0.f, 0.f};
            c = __builtin_amdgcn_mfma_f32_16x16x32_bf16(a0, b0, c, 0, 0, 0);
            c = __builtin_amdgcn_mfma_f32_16x16x32_bf16(a1, b1, c, 0, 0, 0);
            const int o = nt * 16 + r16;
            #pragma unroll
            for (int r = 0; r < 4; ++r) {
                const int p = p0 + r;
                if (p < ne) tpw[(size_t)p * 512 + o] = c[r];
            }
        }
    }
}

// ---------------- K3: CSR gather per node (chunk-clipped) --------
__global__ __launch_bounds__(128) void k_gather(
    const int*    __restrict__ row,
    const int*    __restrict__ snds,
    const float4* __restrict__ eas,
    const float*  __restrict__ tpw,
    const float*  __restrict__ s_up,
    const float*  __restrict__ v_up,
    float*        __restrict__ msg,
    int c0, int c1, int accum) {
    const int nidx = blockIdx.x;
    const int c = threadIdx.x;      // 128 threads, one channel each
    int beg = row[nidx];
    int end = row[nidx + 1];
    if (beg < c0) beg = c0;
    if (end > c1) end = c1;
    if (accum && beg >= end) return;

    float a0 = 0.f, a1 = 0.f, a2 = 0.f, a3 = 0.f,
          a4 = 0.f, a5 = 0.f, a6 = 0.f, a7 = 0.f;

    #pragma unroll 4
    for (int i = beg; i < end; ++i) {
        const int snd = snds[i];
        const float4 ea = eas[i];
        const float y0 = ea.x, y10 = ea.y, y11 = ea.z, y12 = ea.w;

        const float4 t = *(const float4*)(tpw + (size_t)(i - c0) * 512 + c * 4);
        const float se  = s_up[(size_t)snd * 128 + c];
        const float ve0 = v_up[(size_t)snd * 384 + 3 * c + 0];
        const float ve1 = v_up[(size_t)snd * 384 + 3 * c + 1];
        const float ve2 = v_up[(size_t)snd * 384 + 3 * c + 2];

        a0 = fmaf(C000 * t.x * y0, se, a0);
        const float dvy = ve0 * y10 + ve1 * y11 + ve2 * y12;
        a1 = fmaf(C110 * t.w, dvy, a1);
        const float c011t = C011 * t.y * se;
        a2 = fmaf(c011t, y10, a2);
        a3 = fmaf(c011t, y11, a3);
        a4 = fmaf(c011t, y12, a4);
        const float c101t = C101 * t.z * y0;
        a5 = fmaf(c101t, ve0, a5);
        a6 = fmaf(c101t, ve1, a6);
        a7 = fmaf(c101t, ve2, a7);
    }

    float* m = msg + (size_t)nidx * 1024;
    if (accum) {
        m[c]               += a0;
        m[128 + c]         += a1;
        m[256 + 3 * c + 0] += a2;
        m[256 + 3 * c + 1] += a3;
        m[256 + 3 * c + 2] += a4;
        m[640 + 3 * c + 0] += a5;
        m[640 + 3 * c + 1] += a6;
        m[640 + 3 * c + 2] += a7;
    } else {
        m[c]               = a0;
        m[128 + c]         = a1;
        m[256 + 3 * c + 0] = a2;
        m[256 + 3 * c + 1] = a3;
        m[256 + 3 * c + 2] = a4;
        m[640 + 3 * c + 0] = a5;
        m[640 + 3 * c + 1] = a6;
        m[640 + 3 * c + 2] = a7;
    }
}

// ---------------- K4: final node linear (f32, unchanged) ----------------
#define NPB3 8
__global__ void k_node_out(const float* __restrict__ msg,
                           const float* __restrict__ Wls,
                           const float* __restrict__ Wlv,
                           float* __restrict__ out) {
    __shared__ float lds[NPB3][1024];
    const int n0 = blockIdx.x * NPB3;
    const int tid = threadIdx.x;  // 128 threads

    const float4* src = (const float4*)(msg + (size_t)n0 * 1024);
    float4* dst = (float4*)(&lds[0][0]);
    #pragma unroll
    for (int i = 0; i < 2 * NPB3; ++i) dst[tid + 128 * i] = src[tid + 128 * i];
    __syncthreads();

    const int d = tid;
    float acc_s[NPB3];
    float acc_v[NPB3][3];
    #pragma unroll
    for (int p = 0; p < NPB3; ++p) {
        acc_s[p] = 0.f; acc_v[p][0] = 0.f; acc_v[p][1] = 0.f; acc_v[p][2] = 0.f;
    }
    for (int c = 0; c < 256; ++c) {
        float wls = Wls[c * 128 + d];
        float wlv = Wlv[c * 128 + d];
        #pragma unroll
        for (int p = 0; p < NPB3; ++p) {
            acc_s[p]    = fmaf(lds[p][c],               wls, acc_s[p]);
            acc_v[p][0] = fmaf(lds[p][256 + 3*c + 0],   wlv, acc_v[p][0]);
            acc_v[p][1] = fmaf(lds[p][256 + 3*c + 1],   wlv, acc_v[p][1]);
            acc_v[p][2] = fmaf(lds[p][256 + 3*c + 2],   wlv, acc_v[p][2]);
        }
    }
    #pragma unroll
    for (int p = 0; p < NPB3; ++p) {
        int n = n0 + p;
        out[(size_t)n * 512 + d]             = acc_s[p]    * OUT_SCALE;
        out[(size_t)n * 512 + 128 + 3*d + 0] = acc_v[p][0] * OUT_SCALE;
        out[(size_t)n * 512 + 128 + 3*d + 1] = acc_v[p][1] * OUT_SCALE;
        out[(size_t)n * 512 + 128 + 3*d + 2] = acc_v[p][2] * OUT_SCALE;
    }
}

extern "C" void kernel_launch(void* const* d_in, const int* in_sizes, int n_in,
                              void* d_out, int out_size, void* d_ws, size_t ws_size,
                              hipStream_t stream) {
    const float* node_feats = (const float*)d_in[1];
    const float* edge_attrs = (const float*)d_in[2];
    const float* edge_feats = (const float*)d_in[3];
    const int*   edge_index = (const int*)d_in[4];
    const float* W_up_s = (const float*)d_in[5];
    const float* W_up_v = (const float*)d_in[6];
    const float* W_mlp1 = (const float*)d_in[7];
    const float* W_mlp2 = (const float*)d_in[8];
    const float* W_mlp3 = (const float*)d_in[9];
    const float* W_mlp4 = (const float*)d_in[10];
    const float* W_lin_s = (const float*)d_in[11];
    const float* W_lin_v = (const float*)d_in[12];

    float* ws     = (float*)d_ws;
    float* s_up   = ws + S_UP_OFF;
    float* v_up   = ws + V_UP_OFF;
    float* msg    = ws + MSG_OFF;
    short* W2p    = (short*)(ws + WP_OFF);          // 4096 shorts
    short* W3p    = W2p + 4096;
    short* W4p    = W3p + 4096;                     // 32768 shorts
    int*   row    = (int*)(ws + ROW_OFF);
    int*   elist  = (int*)(ws + ELIST_OFF);
    int*   snds   = (int*)(ws + SNDS_OFF);
    float4* eas   = (float4*)(ws + EAS_OFF);
    float* tpw    = ws + TPW_OFF;
    // cnt/cursor live inside the msg region; gather chunk-0 overwrites msg
    int*   cnt    = (int*)msg;
    int*   cursor = cnt + N_NODES;
    float* out_f  = (float*)d_out;

    // adaptive chunking from actual ws_size (deterministic across calls)
    size_t total_f = ws_size / 4;
    if (total_f > MAX_TOTAL_F) total_f = MAX_TOTAL_F;
    size_t cap_f = (total_f > TPW_OFF) ? (total_f - TPW_OFF) : 0;
    long long ce = (long long)(cap_f / 512);
    ce &= ~63LL;
    if (ce < 64) ce = 64;
    if (ce > N_EDGES) ce = N_EDGES;
    const int chunkE = (int)ce;
    const int nch = (N_EDGES + chunkE - 1) / chunkE;

    (void)hipMemsetAsync(cnt, 0, 2 * N_NODES * sizeof(int), stream);
    k_pack<<<160, 256, 0, stream>>>(W_mlp2, W_mlp3, W_mlp4, W2p, W3p, W4p);
    k_node_up<<<N_NODES / NPB, 128, 0, stream>>>(node_feats, W_up_s, W_up_v, s_up, v_up);
    k_hist<<<N_EDGES / 256, 256, 0, stream>>>(edge_index, cnt);
    k_scan<<<1, 256, 0, stream>>>(cnt, row, cursor);
    k_scatter<<<N_EDGES / 256, 256, 0, stream>>>(edge_index, cursor, edge_attrs,
                                                 elist, snds, eas);

    for (int ch = 0; ch < nch; ++ch) {
        const int c0 = ch * chunkE;
        const int c1 = (c0 + chunkE < N_EDGES) ? c0 + chunkE : N_EDGES;
        const int ne = c1 - c0;
        k_edge_mfma<<<(ne + 63) / 64, 256, 0, stream>>>(
            edge_feats, W_mlp1, W2p, W3p, W4p, elist, c0, ne, tpw);
        k_gather<<<N_NODES, 128, 0, stream>>>(
            row, snds, eas, tpw, s_up, v_up, msg, c0, c1, ch == 0 ? 0 : 1);
    }
    k_node_out<<<N_NODES / NPB3, 128, 0, stream>>>(msg, W_lin_s, W_lin_v, out_f);
}

// Round 8
// 386.326 us; speedup vs baseline: 9.2633x; 1.2397x over previous
//
#include <hip/hip_runtime.h>

// MACE node message block. bf16-MFMA edge MLP + CSR gather + MFMA node_out.
// N=10000, E=160000, C=128, RB=8, HID=64.
//
// ws layout (float units):
//   [0 .. 1.28M)        s_up (N,128)
//   [1.28M .. 5.12M)    v_up (N,128,3)
//   [5.12M .. 15.36M)   msg (N,1024) = [s0|s1|v0|v1|v2 planes]; cnt/cursor pre-gather
//   [15.36M .. +53248)  packed bf16 weights: W2p W3p W4p Wlsp Wlvp
//   [15413248 +10001]   row (int)
//   [15423252 +160000]  elist (int)
//   [15583252 +160000]  snds (int)
//   [15743252 +640000]  eas (float4)
//   [16383252 .. )      tpw chunk buffer [pos][512] f32
// cap total at <= 97,482,772 floats (389.93 MB, proven fit R4-R7)

#define N_NODES 10000
#define N_EDGES 160000

#define S_UP_OFF   0u
#define V_UP_OFF   1280000u
#define MSG_OFF    5120000u
#define WP_OFF     15360000u
#define ROW_OFF    15413248u
#define ELIST_OFF  15423252u
#define SNDS_OFF   15583252u
#define EAS_OFF    15743252u
#define TPW_OFF    16383252u
#define MAX_TOTAL_F 97482772u

typedef __attribute__((ext_vector_type(8))) short bf16x8;
typedef __attribute__((ext_vector_type(4))) float f32x4;

__device__ __forceinline__ float silu(float x) {
    return x / (1.0f + __expf(-x));
}
__device__ __forceinline__ short f2bf(float x) {
    unsigned u = __float_as_uint(x);
    unsigned r = (u + 0x7FFFu + ((u >> 16) & 1u)) >> 16;
    return (short)r;
}

constexpr float INV_SQRT_C  = 0.08838834764831845f;
constexpr float INV_SQRT_RB = 0.35355339059327373f;
constexpr float INV_SQRT_H  = 0.125f;
constexpr float OUT_SCALE   = 0.0625f * 0.0625f;      // 1/sqrt(256) / AVG_NEIGH
constexpr float C000 = 0.7071067811865476f;
constexpr float C110 = 0.4082482904638631f;
constexpr float C011 = 0.7071067811865476f;
constexpr float C101 = 0.7071067811865476f;

// ---------------- K0: pack weights into bf16 MFMA B-fragment order ----------
// MLP frag order: [ntile][ktile][lane][e], k = kt*32+(l>>4)*8+e, col = nt*16+(l&15).
// Wls/Wlv frag order: [((nt*8+kt)*64+l)*8+e], k as above, d = nt*16+(l&15).
__global__ void k_pack(const float* __restrict__ W2, const float* __restrict__ W3,
                       const float* __restrict__ W4,
                       const float* __restrict__ Wls, const float* __restrict__ Wlv,
                       short* __restrict__ W2p, short* __restrict__ W3p,
                       short* __restrict__ W4p,
                       short* __restrict__ Wlsp, short* __restrict__ Wlvp) {
    int idx = blockIdx.x * 256 + threadIdx.x;   // 106496 total
    if (idx < 4096) {
        int i2 = idx;
        int e = i2 & 7, l = (i2 >> 3) & 63, kt = (i2 >> 9) & 1, nt = i2 >> 10;
        int k = kt * 32 + (l >> 4) * 8 + e;
        int col = nt * 16 + (l & 15);
        W2p[i2] = f2bf(W2[k * 64 + col] * INV_SQRT_H);
    } else if (idx < 8192) {
        int i2 = idx - 4096;
        int e = i2 & 7, l = (i2 >> 3) & 63, kt = (i2 >> 9) & 1, nt = i2 >> 10;
        int k = kt * 32 + (l >> 4) * 8 + e;
        int col = nt * 16 + (l & 15);
        W3p[i2] = f2bf(W3[k * 64 + col] * INV_SQRT_H);
    } else if (idx < 40960) {
        int i2 = idx - 8192;
        int e = i2 & 7, l = (i2 >> 3) & 63, kt = (i2 >> 9) & 1, nt = i2 >> 10; // nt 0..31
        int k = kt * 32 + (l >> 4) * 8 + e;
        int o = nt * 16 + (l & 15);      // o = c*4 + a
        int c = o >> 2, a = o & 3;
        W4p[i2] = f2bf(W4[k * 512 + a * 128 + c] * INV_SQRT_H);
    } else if (idx < 73728) {
        int i2 = idx - 40960;
        int e = i2 & 7, l = (i2 >> 3) & 63, kt = (i2 >> 9) & 7, nt = (i2 >> 12) & 7;
        int k = kt * 32 + (l >> 4) * 8 + e;
        int d = nt * 16 + (l & 15);
        Wlsp[i2] = f2bf(Wls[k * 128 + d] * OUT_SCALE);
    } else if (idx < 106496) {
        int i2 = idx - 73728;
        int e = i2 & 7, l = (i2 >> 3) & 63, kt = (i2 >> 9) & 7, nt = (i2 >> 12) & 7;
        int k = kt * 32 + (l >> 4) * 8 + e;
        int d = nt * 16 + (l & 15);
        Wlvp[i2] = f2bf(Wlv[k * 128 + d] * OUT_SCALE);
    }
}

// ---------------- K1: node up-projection (f32, unchanged) ----------------
#define NPB 8
__global__ void k_node_up(const float* __restrict__ nf,
                          const float* __restrict__ Wus,
                          const float* __restrict__ Wuv,
                          float* __restrict__ s_up,
                          float* __restrict__ v_up) {
    __shared__ float lds[NPB][512];
    const int n0 = blockIdx.x * NPB;
    const int tid = threadIdx.x;  // 128 threads

    const float4* src = (const float4*)(nf + (size_t)n0 * 512);
    float4* dst = (float4*)(&lds[0][0]);
    #pragma unroll
    for (int i = 0; i < NPB; ++i) dst[tid + 128 * i] = src[tid + 128 * i];
    __syncthreads();

    const int d = tid;
    float acc_s[NPB];
    float acc_v[NPB][3];
    #pragma unroll
    for (int p = 0; p < NPB; ++p) {
        acc_s[p] = 0.f; acc_v[p][0] = 0.f; acc_v[p][1] = 0.f; acc_v[p][2] = 0.f;
    }
    for (int c = 0; c < 128; ++c) {
        float ws = Wus[c * 128 + d];
        float wv = Wuv[c * 128 + d];
        #pragma unroll
        for (int p = 0; p < NPB; ++p) {
            acc_s[p]    = fmaf(lds[p][c],             ws, acc_s[p]);
            acc_v[p][0] = fmaf(lds[p][128 + 3*c + 0], wv, acc_v[p][0]);
            acc_v[p][1] = fmaf(lds[p][128 + 3*c + 1], wv, acc_v[p][1]);
            acc_v[p][2] = fmaf(lds[p][128 + 3*c + 2], wv, acc_v[p][2]);
        }
    }
    #pragma unroll
    for (int p = 0; p < NPB; ++p) {
        int n = n0 + p;
        s_up[(size_t)n * 128 + d]         = acc_s[p]    * INV_SQRT_C;
        v_up[(size_t)n * 384 + 3*d + 0]   = acc_v[p][0] * INV_SQRT_C;
        v_up[(size_t)n * 384 + 3*d + 1]   = acc_v[p][1] * INV_SQRT_C;
        v_up[(size_t)n * 384 + 3*d + 2]   = acc_v[p][2] * INV_SQRT_C;
    }
}

// ---------------- CSR build ----------------
__global__ void k_hist(const int* __restrict__ ei, int* __restrict__ cnt) {
    int e = blockIdx.x * 256 + threadIdx.x;
    if (e < N_EDGES) atomicAdd(&cnt[ei[N_EDGES + e]], 1);
}

__global__ void k_scan(const int* __restrict__ cnt, int* __restrict__ row,
                       int* __restrict__ cursor) {
    __shared__ int part[256];
    const int t = threadIdx.x;
    const int base = t * 40;
    int s = 0;
    for (int i = 0; i < 40; ++i) {
        int idx = base + i;
        s += (idx < N_NODES) ? cnt[idx] : 0;
    }
    part[t] = s;
    __syncthreads();
    for (int off = 1; off < 256; off <<= 1) {
        int v = (t >= off) ? part[t - off] : 0;
        __syncthreads();
        part[t] += v;
        __syncthreads();
    }
    int run = part[t] - s;   // exclusive prefix
    for (int i = 0; i < 40; ++i) {
        int idx = base + i;
        if (idx < N_NODES) {
            row[idx] = run;
            cursor[idx] = run;
            run += cnt[idx];
        }
    }
    if (t == 255) row[N_NODES] = part[255];
}

__global__ void k_scatter(const int* __restrict__ ei, int* __restrict__ cursor,
                          const float* __restrict__ edge_attrs,
                          int* __restrict__ elist, int* __restrict__ snds,
                          float4* __restrict__ eas) {
    int e = blockIdx.x * 256 + threadIdx.x;
    if (e < N_EDGES) {
        int snd = ei[e];
        int r = ei[N_EDGES + e];
        int pos = atomicAdd(&cursor[r], 1);
        elist[pos] = e;
        snds[pos] = snd;
        eas[pos] = ((const float4*)edge_attrs)[e];
    }
}

// ---------------- K2: bf16-MFMA edge MLP -> tpw[pos][512] f32 ----------------
__global__ __launch_bounds__(256) void k_edge_mfma(
    const float* __restrict__ edge_feats,
    const float* __restrict__ W1,
    const short* __restrict__ W2p,
    const short* __restrict__ W3p,
    const short* __restrict__ W4p,
    const int*   __restrict__ elist,
    int c0, int ne,
    float*       __restrict__ tpw) {
    __shared__ __align__(16) short h0[64][72];   // padded: 2-way banks only
    __shared__ __align__(16) short h1[64][72];

    const int tid = threadIdx.x;
    const int l   = tid & 63;
    const int w   = tid >> 6;
    const int r16 = l & 15;
    const int g4  = l >> 4;
    const int base = blockIdx.x * 64;
    const int erow = w * 16 + r16;               // this lane's edge row

    // ---- layer 1 (f32 VALU)
    {
        const int pos = base + erow;
        const int e = elist[c0 + ((pos < ne) ? pos : 0)];
        float4 f0 = ((const float4*)edge_feats)[(size_t)e * 2 + 0];
        float4 f1 = ((const float4*)edge_feats)[(size_t)e * 2 + 1];
        float ef[8] = {f0.x, f0.y, f0.z, f0.w, f1.x, f1.y, f1.z, f1.w};
        const int j0 = g4 * 16;
        float acc[16];
        #pragma unroll
        for (int jj = 0; jj < 16; ++jj) acc[jj] = 0.f;
        #pragma unroll
        for (int k = 0; k < 8; ++k) {
            const float* wr = W1 + k * 64 + j0;
            float4 w0 = *(const float4*)(wr + 0);
            float4 w1 = *(const float4*)(wr + 4);
            float4 w2 = *(const float4*)(wr + 8);
            float4 w3 = *(const float4*)(wr + 12);
            const float hk = ef[k];
            acc[0]  = fmaf(hk, w0.x, acc[0]);  acc[1]  = fmaf(hk, w0.y, acc[1]);
            acc[2]  = fmaf(hk, w0.z, acc[2]);  acc[3]  = fmaf(hk, w0.w, acc[3]);
            acc[4]  = fmaf(hk, w1.x, acc[4]);  acc[5]  = fmaf(hk, w1.y, acc[5]);
            acc[6]  = fmaf(hk, w1.z, acc[6]);  acc[7]  = fmaf(hk, w1.w, acc[7]);
            acc[8]  = fmaf(hk, w2.x, acc[8]);  acc[9]  = fmaf(hk, w2.y, acc[9]);
            acc[10] = fmaf(hk, w2.z, acc[10]); acc[11] = fmaf(hk, w2.w, acc[11]);
            acc[12] = fmaf(hk, w3.x, acc[12]); acc[13] = fmaf(hk, w3.y, acc[13]);
            acc[14] = fmaf(hk, w3.z, acc[14]); acc[15] = fmaf(hk, w3.w, acc[15]);
        }
        unsigned pk[8];
        #pragma unroll
        for (int q = 0; q < 8; ++q) {
            unsigned lo = (unsigned short)f2bf(silu(acc[2*q]     * INV_SQRT_RB));
            unsigned hi = (unsigned short)f2bf(silu(acc[2*q + 1] * INV_SQRT_RB));
            pk[q] = lo | (hi << 16);
        }
        uint4 A; A.x = pk[0]; A.y = pk[1]; A.z = pk[2]; A.w = pk[3];
        uint4 B; B.x = pk[4]; B.y = pk[5]; B.z = pk[6]; B.w = pk[7];
        *(uint4*)&h0[erow][j0]     = A;
        *(uint4*)&h0[erow][j0 + 8] = B;
    }

    // ---- layer 2: h0 -> h1
    {
        bf16x8 a0 = *(const bf16x8*)&h0[erow][g4 * 8];
        bf16x8 a1 = *(const bf16x8*)&h0[erow][32 + g4 * 8];
        #pragma unroll
        for (int nt = 0; nt < 4; ++nt) {
            bf16x8 b0 = *(const bf16x8*)(W2p + ((nt * 2 + 0) * 64 + l) * 8);
            bf16x8 b1 = *(const bf16x8*)(W2p + ((nt * 2 + 1) * 64 + l) * 8);
            f32x4 c = {0.f, 0.f, 0.f, 0.f};
            c = __builtin_amdgcn_mfma_f32_16x16x32_bf16(a0, b0, c, 0, 0, 0);
            c = __builtin_amdgcn_mfma_f32_16x16x32_bf16(a1, b1, c, 0, 0, 0);
            #pragma unroll
            for (int r = 0; r < 4; ++r)
                h1[w * 16 + g4 * 4 + r][nt * 16 + r16] = f2bf(silu(c[r]));
        }
    }

    // ---- layer 3: h1 -> h0
    {
        bf16x8 a0 = *(const bf16x8*)&h1[erow][g4 * 8];
        bf16x8 a1 = *(const bf16x8*)&h1[erow][32 + g4 * 8];
        #pragma unroll
        for (int nt = 0; nt < 4; ++nt) {
            bf16x8 b0 = *(const bf16x8*)(W3p + ((nt * 2 + 0) * 64 + l) * 8);
            bf16x8 b1 = *(const bf16x8*)(W3p + ((nt * 2 + 1) * 64 + l) * 8);
            f32x4 c = {0.f, 0.f, 0.f, 0.f};
            c = __builtin_amdgcn_mfma_f32_16x16x32_bf16(a0, b0, c, 0, 0, 0);
            c = __builtin_amdgcn_mfma_f32_16x16x32_bf16(a1, b1, c, 0, 0, 0);
            #pragma unroll
            for (int r = 0; r < 4; ++r)
                h0[w * 16 + g4 * 4 + r][nt * 16 + r16] = f2bf(silu(c[r]));
        }
    }

    // ---- layer 4: h0 @ W4p -> tpw
    {
        bf16x8 a0 = *(const bf16x8*)&h0[erow][g4 * 8];
        bf16x8 a1 = *(const bf16x8*)&h0[erow][32 + g4 * 8];
        const int p0 = base + w * 16 + g4 * 4;
        #pragma unroll 2
        for (int nt = 0; nt < 32; ++nt) {
            bf16x8 b0 = *(const bf16x8*)(W4p + ((nt * 2 + 0) * 64 + l) * 8);
            bf16x8 b1 = *(const bf16x8*)(W4p + ((nt * 2 + 1) * 64 + l) * 8);
            f32x4 c = {0.f, 0.f, 0.f, 0.f};
            c = __builtin_amdgcn_mfma_f32_16x16x32_bf16(a0, b0, c, 0, 0, 0);
            c = __builtin_amdgcn_mfma_f32_16x16x32_bf16(a1, b1, c, 0, 0, 0);
            const int o = nt * 16 + r16;
            #pragma unroll
            for (int r = 0; r < 4; ++r) {
                const int p = p0 + r;
                if (p < ne) tpw[(size_t)p * 512 + o] = c[r];
            }
        }
    }
}

// ---------------- K3: CSR gather per node (chunk-clipped) --------
// msg layout: [s0(128) | s1(128) | v m=0 (256) | m=1 (256) | m=2 (256)]
__global__ __launch_bounds__(128) void k_gather(
    const int*    __restrict__ row,
    const int*    __restrict__ snds,
    const float4* __restrict__ eas,
    const float*  __restrict__ tpw,
    const float*  __restrict__ s_up,
    const float*  __restrict__ v_up,
    float*        __restrict__ msg,
    int c0, int c1, int accum) {
    const int nidx = blockIdx.x;
    const int c = threadIdx.x;      // 128 threads, one channel each
    int beg = row[nidx];
    int end = row[nidx + 1];
    if (beg < c0) beg = c0;
    if (end > c1) end = c1;
    if (accum && beg >= end) return;

    float a0 = 0.f, a1 = 0.f, a2 = 0.f, a3 = 0.f,
          a4 = 0.f, a5 = 0.f, a6 = 0.f, a7 = 0.f;

    #pragma unroll 4
    for (int i = beg; i < end; ++i) {
        const int snd = snds[i];
        const float4 ea = eas[i];
        const float y0 = ea.x, y10 = ea.y, y11 = ea.z, y12 = ea.w;

        const float4 t = *(const float4*)(tpw + (size_t)(i - c0) * 512 + c * 4);
        const float se  = s_up[(size_t)snd * 128 + c];
        const float ve0 = v_up[(size_t)snd * 384 + 3 * c + 0];
        const float ve1 = v_up[(size_t)snd * 384 + 3 * c + 1];
        const float ve2 = v_up[(size_t)snd * 384 + 3 * c + 2];

        a0 = fmaf(C000 * t.x * y0, se, a0);
        const float dvy = ve0 * y10 + ve1 * y11 + ve2 * y12;
        a1 = fmaf(C110 * t.w, dvy, a1);
        const float c011t = C011 * t.y * se;
        a2 = fmaf(c011t, y10, a2);
        a3 = fmaf(c011t, y11, a3);
        a4 = fmaf(c011t, y12, a4);
        const float c101t = C101 * t.z * y0;
        a5 = fmaf(c101t, ve0, a5);
        a6 = fmaf(c101t, ve1, a6);
        a7 = fmaf(c101t, ve2, a7);
    }

    float* m = msg + (size_t)nidx * 1024;
    if (accum) {
        m[c]             += a0;
        m[128 + c]       += a1;
        m[256 + c]       += a2;   // v plane m=0, k = c
        m[512 + c]       += a3;   // v plane m=1
        m[768 + c]       += a4;   // v plane m=2
        m[256 + 128 + c] += a5;   // v plane m=0, k = 128+c
        m[512 + 128 + c] += a6;
        m[768 + 128 + c] += a7;
    } else {
        m[c]             = a0;
        m[128 + c]       = a1;
        m[256 + c]       = a2;
        m[512 + c]       = a3;
        m[768 + c]       = a4;
        m[256 + 128 + c] = a5;
        m[512 + 128 + c] = a6;
        m[768 + 128 + c] = a7;
    }
}

// ---------------- K4: final node linear, MFMA ----------------
// 1 wave per block, 16 nodes. 4 GEMMs (s, v0, v1, v2), K=256, Nout=128.
__global__ __launch_bounds__(64) void k_node_out(
    const float* __restrict__ msg,
    const short* __restrict__ Wlsp,
    const short* __restrict__ Wlvp,
    float*       __restrict__ out) {
    const int l   = threadIdx.x;     // 0..63
    const int r16 = l & 15;
    const int g4  = l >> 4;
    const int n0  = blockIdx.x * 16;
    const float* mrow = msg + (size_t)(n0 + r16) * 1024;

    #pragma unroll
    for (int sec = 0; sec < 4; ++sec) {
        const short* Wp = (sec == 0) ? Wlsp : Wlvp;
        // A fragments for this section: 8 k-tiles
        bf16x8 a[8];
        #pragma unroll
        for (int kt = 0; kt < 8; ++kt) {
            const float* p = mrow + sec * 256 + kt * 32 + g4 * 8;
            float4 x0 = *(const float4*)p;
            float4 x1 = *(const float4*)(p + 4);
            bf16x8 t;
            t[0] = f2bf(x0.x); t[1] = f2bf(x0.y); t[2] = f2bf(x0.z); t[3] = f2bf(x0.w);
            t[4] = f2bf(x1.x); t[5] = f2bf(x1.y); t[6] = f2bf(x1.z); t[7] = f2bf(x1.w);
            a[kt] = t;
        }
        #pragma unroll
        for (int nt = 0; nt < 8; ++nt) {
            f32x4 c = {0.f, 0.f, 0.f, 0.f};
            #pragma unroll
            for (int kt = 0; kt < 8; ++kt) {
                bf16x8 b = *(const bf16x8*)(Wp + ((nt * 8 + kt) * 64 + l) * 8);
                c = __builtin_amdgcn_mfma_f32_16x16x32_bf16(a[kt], b, c, 0, 0, 0);
            }
            const int d = nt * 16 + r16;
            #pragma unroll
            for (int r = 0; r < 4; ++r) {
                const size_t n = n0 + g4 * 4 + r;
                if (sec == 0) out[n * 512 + d] = c[r];
                else          out[n * 512 + 128 + 3 * d + (sec - 1)] = c[r];
            }
        }
    }
}

extern "C" void kernel_launch(void* const* d_in, const int* in_sizes, int n_in,
                              void* d_out, int out_size, void* d_ws, size_t ws_size,
                              hipStream_t stream) {
    const float* node_feats = (const float*)d_in[1];
    const float* edge_attrs = (const float*)d_in[2];
    const float* edge_feats = (const float*)d_in[3];
    const int*   edge_index = (const int*)d_in[4];
    const float* W_up_s = (const float*)d_in[5];
    const float* W_up_v = (const float*)d_in[6];
    const float* W_mlp1 = (const float*)d_in[7];
    const float* W_mlp2 = (const float*)d_in[8];
    const float* W_mlp3 = (const float*)d_in[9];
    const float* W_mlp4 = (const float*)d_in[10];
    const float* W_lin_s = (const float*)d_in[11];
    const float* W_lin_v = (const float*)d_in[12];

    float* ws     = (float*)d_ws;
    float* s_up   = ws + S_UP_OFF;
    float* v_up   = ws + V_UP_OFF;
    float* msg    = ws + MSG_OFF;
    short* W2p    = (short*)(ws + WP_OFF);   // 4096 shorts
    short* W3p    = W2p + 4096;              // 4096
    short* W4p    = W3p + 4096;              // 32768
    short* Wlsp   = W4p + 32768;             // 32768
    short* Wlvp   = Wlsp + 32768;            // 32768
    int*   row    = (int*)(ws + ROW_OFF);
    int*   elist  = (int*)(ws + ELIST_OFF);
    int*   snds   = (int*)(ws + SNDS_OFF);
    float4* eas   = (float4*)(ws + EAS_OFF);
    float* tpw    = ws + TPW_OFF;
    int*   cnt    = (int*)msg;
    int*   cursor = cnt + N_NODES;
    float* out_f  = (float*)d_out;

    // adaptive chunking from actual ws_size (deterministic across calls)
    size_t total_f = ws_size / 4;
    if (total_f > MAX_TOTAL_F) total_f = MAX_TOTAL_F;
    size_t cap_f = (total_f > TPW_OFF) ? (total_f - TPW_OFF) : 0;
    long long ce = (long long)(cap_f / 512);
    ce &= ~63LL;
    if (ce < 64) ce = 64;
    if (ce > N_EDGES) ce = N_EDGES;
    const int chunkE = (int)ce;
    const int nch = (N_EDGES + chunkE - 1) / chunkE;

    (void)hipMemsetAsync(cnt, 0, 2 * N_NODES * sizeof(int), stream);
    k_pack<<<416, 256, 0, stream>>>(W_mlp2, W_mlp3, W_mlp4, W_lin_s, W_lin_v,
                                    W2p, W3p, W4p, Wlsp, Wlvp);
    k_node_up<<<N_NODES / NPB, 128, 0, stream>>>(node_feats, W_up_s, W_up_v, s_up, v_up);
    k_hist<<<N_EDGES / 256, 256, 0, stream>>>(edge_index, cnt);
    k_scan<<<1, 256, 0, stream>>>(cnt, row, cursor);
    k_scatter<<<N_EDGES / 256, 256, 0, stream>>>(edge_index, cursor, edge_attrs,
                                                 elist, snds, eas);

    for (int ch = 0; ch < nch; ++ch) {
        const int c0 = ch * chunkE;
        const int c1 = (c0 + chunkE < N_EDGES) ? c0 + chunkE : N_EDGES;
        const int ne = c1 - c0;
        k_edge_mfma<<<(ne + 63) / 64, 256, 0, stream>>>(
            edge_feats, W_mlp1, W2p, W3p, W4p, elist, c0, ne, tpw);
        k_gather<<<N_NODES, 128, 0, stream>>>(
            row, snds, eas, tpw, s_up, v_up, msg, c0, c1, ch == 0 ? 0 : 1);
    }
    k_node_out<<<625, 64, 0, stream>>>(msg, Wlsp, Wlvp, out_f);
}

// Round 9
// 346.416 us; speedup vs baseline: 10.3305x; 1.1152x over previous
//
#include <hip/hip_runtime.h>

// MACE node message block. bf16-MFMA edge MLP + CSR gather + MFMA node_out.
// N=10000, E=160000, C=128, RB=8, HID=64.
//
// ws layout (float units):
//   [0 .. 1.28M)        s_up (N,128)
//   [1.28M .. 5.12M)    v_up (N,128,3)
//   [5.12M .. 15.36M)   msg (N,1024) = [s0|s1|v0|v1|v2 planes]; cnt/cursor pre-gather
//   [15.36M .. +53248)  packed bf16 weights: W2p W3p W4p Wlsp Wlvp
//   [15413248 +10001]   row (int)
//   [15423252 +160000]  elist (int)
//   [15583252 +160000]  snds (int)
//   [15743252 +640000]  eas (float4)
//   [16383252 .. )      tpw chunk buffer [pos][512] f32
// cap total at <= 97,482,772 floats (389.93 MB, proven fit R4-R8)

#define N_NODES 10000
#define N_EDGES 160000

#define S_UP_OFF   0u
#define V_UP_OFF   1280000u
#define MSG_OFF    5120000u
#define WP_OFF     15360000u
#define ROW_OFF    15413248u
#define ELIST_OFF  15423252u
#define SNDS_OFF   15583252u
#define EAS_OFF    15743252u
#define TPW_OFF    16383252u
#define MAX_TOTAL_F 97482772u

typedef __attribute__((ext_vector_type(8))) short bf16x8;
typedef __attribute__((ext_vector_type(4))) float f32x4;

__device__ __forceinline__ float silu(float x) {
    return x / (1.0f + __expf(-x));
}
__device__ __forceinline__ short f2bf(float x) {
    unsigned u = __float_as_uint(x);
    unsigned r = (u + 0x7FFFu + ((u >> 16) & 1u)) >> 16;
    return (short)r;
}

constexpr float INV_SQRT_C  = 0.08838834764831845f;
constexpr float INV_SQRT_RB = 0.35355339059327373f;
constexpr float INV_SQRT_H  = 0.125f;
constexpr float OUT_SCALE   = 0.0625f * 0.0625f;      // 1/sqrt(256) / AVG_NEIGH
constexpr float C000 = 0.7071067811865476f;
constexpr float C110 = 0.4082482904638631f;
constexpr float C011 = 0.7071067811865476f;
constexpr float C101 = 0.7071067811865476f;

// ---------------- K0: pack weights into bf16 MFMA B-fragment order ----------
// MLP frag order: [ntile][ktile][lane][e], k = kt*32+(l>>4)*8+e, col = nt*16+(l&15).
// Wls/Wlv frag order: [((nt*8+kt)*64+l)*8+e], k as above, d = nt*16+(l&15).
__global__ void k_pack(const float* __restrict__ W2, const float* __restrict__ W3,
                       const float* __restrict__ W4,
                       const float* __restrict__ Wls, const float* __restrict__ Wlv,
                       short* __restrict__ W2p, short* __restrict__ W3p,
                       short* __restrict__ W4p,
                       short* __restrict__ Wlsp, short* __restrict__ Wlvp) {
    int idx = blockIdx.x * 256 + threadIdx.x;   // 106496 total
    if (idx < 4096) {
        int i2 = idx;
        int e = i2 & 7, l = (i2 >> 3) & 63, kt = (i2 >> 9) & 1, nt = i2 >> 10;
        int k = kt * 32 + (l >> 4) * 8 + e;
        int col = nt * 16 + (l & 15);
        W2p[i2] = f2bf(W2[k * 64 + col] * INV_SQRT_H);
    } else if (idx < 8192) {
        int i2 = idx - 4096;
        int e = i2 & 7, l = (i2 >> 3) & 63, kt = (i2 >> 9) & 1, nt = i2 >> 10;
        int k = kt * 32 + (l >> 4) * 8 + e;
        int col = nt * 16 + (l & 15);
        W3p[i2] = f2bf(W3[k * 64 + col] * INV_SQRT_H);
    } else if (idx < 40960) {
        int i2 = idx - 8192;
        int e = i2 & 7, l = (i2 >> 3) & 63, kt = (i2 >> 9) & 1, nt = i2 >> 10; // nt 0..31
        int k = kt * 32 + (l >> 4) * 8 + e;
        int o = nt * 16 + (l & 15);      // o = c*4 + a
        int c = o >> 2, a = o & 3;
        W4p[i2] = f2bf(W4[k * 512 + a * 128 + c] * INV_SQRT_H);
    } else if (idx < 73728) {
        int i2 = idx - 40960;
        int e = i2 & 7, l = (i2 >> 3) & 63, kt = (i2 >> 9) & 7, nt = (i2 >> 12) & 7;
        int k = kt * 32 + (l >> 4) * 8 + e;
        int d = nt * 16 + (l & 15);
        Wlsp[i2] = f2bf(Wls[k * 128 + d] * OUT_SCALE);
    } else if (idx < 106496) {
        int i2 = idx - 73728;
        int e = i2 & 7, l = (i2 >> 3) & 63, kt = (i2 >> 9) & 7, nt = (i2 >> 12) & 7;
        int k = kt * 32 + (l >> 4) * 8 + e;
        int d = nt * 16 + (l & 15);
        Wlvp[i2] = f2bf(Wlv[k * 128 + d] * OUT_SCALE);
    }
}

// ---------------- K1: node up-projection (f32, unchanged) ----------------
#define NPB 8
__global__ void k_node_up(const float* __restrict__ nf,
                          const float* __restrict__ Wus,
                          const float* __restrict__ Wuv,
                          float* __restrict__ s_up,
                          float* __restrict__ v_up) {
    __shared__ float lds[NPB][512];
    const int n0 = blockIdx.x * NPB;
    const int tid = threadIdx.x;  // 128 threads

    const float4* src = (const float4*)(nf + (size_t)n0 * 512);
    float4* dst = (float4*)(&lds[0][0]);
    #pragma unroll
    for (int i = 0; i < NPB; ++i) dst[tid + 128 * i] = src[tid + 128 * i];
    __syncthreads();

    const int d = tid;
    float acc_s[NPB];
    float acc_v[NPB][3];
    #pragma unroll
    for (int p = 0; p < NPB; ++p) {
        acc_s[p] = 0.f; acc_v[p][0] = 0.f; acc_v[p][1] = 0.f; acc_v[p][2] = 0.f;
    }
    for (int c = 0; c < 128; ++c) {
        float ws = Wus[c * 128 + d];
        float wv = Wuv[c * 128 + d];
        #pragma unroll
        for (int p = 0; p < NPB; ++p) {
            acc_s[p]    = fmaf(lds[p][c],             ws, acc_s[p]);
            acc_v[p][0] = fmaf(lds[p][128 + 3*c + 0], wv, acc_v[p][0]);
            acc_v[p][1] = fmaf(lds[p][128 + 3*c + 1], wv, acc_v[p][1]);
            acc_v[p][2] = fmaf(lds[p][128 + 3*c + 2], wv, acc_v[p][2]);
        }
    }
    #pragma unroll
    for (int p = 0; p < NPB; ++p) {
        int n = n0 + p;
        s_up[(size_t)n * 128 + d]         = acc_s[p]    * INV_SQRT_C;
        v_up[(size_t)n * 384 + 3*d + 0]   = acc_v[p][0] * INV_SQRT_C;
        v_up[(size_t)n * 384 + 3*d + 1]   = acc_v[p][1] * INV_SQRT_C;
        v_up[(size_t)n * 384 + 3*d + 2]   = acc_v[p][2] * INV_SQRT_C;
    }
}

// ---------------- CSR build ----------------
__global__ void k_hist(const int* __restrict__ ei, int* __restrict__ cnt) {
    int e = blockIdx.x * 256 + threadIdx.x;
    if (e < N_EDGES) atomicAdd(&cnt[ei[N_EDGES + e]], 1);
}

__global__ void k_scan(const int* __restrict__ cnt, int* __restrict__ row,
                       int* __restrict__ cursor) {
    __shared__ int part[256];
    const int t = threadIdx.x;
    const int base = t * 40;
    int s = 0;
    for (int i = 0; i < 40; ++i) {
        int idx = base + i;
        s += (idx < N_NODES) ? cnt[idx] : 0;
    }
    part[t] = s;
    __syncthreads();
    for (int off = 1; off < 256; off <<= 1) {
        int v = (t >= off) ? part[t - off] : 0;
        __syncthreads();
        part[t] += v;
        __syncthreads();
    }
    int run = part[t] - s;   // exclusive prefix
    for (int i = 0; i < 40; ++i) {
        int idx = base + i;
        if (idx < N_NODES) {
            row[idx] = run;
            cursor[idx] = run;
            run += cnt[idx];
        }
    }
    if (t == 255) row[N_NODES] = part[255];
}

__global__ void k_scatter(const int* __restrict__ ei, int* __restrict__ cursor,
                          const float* __restrict__ edge_attrs,
                          int* __restrict__ elist, int* __restrict__ snds,
                          float4* __restrict__ eas) {
    int e = blockIdx.x * 256 + threadIdx.x;
    if (e < N_EDGES) {
        int snd = ei[e];
        int r = ei[N_EDGES + e];
        int pos = atomicAdd(&cursor[r], 1);
        elist[pos] = e;
        snds[pos] = snd;
        eas[pos] = ((const float4*)edge_attrs)[e];
    }
}

// ---------------- K2: bf16-MFMA edge MLP -> tpw[pos][512] f32 ----------------
__global__ __launch_bounds__(256) void k_edge_mfma(
    const float* __restrict__ edge_feats,
    const float* __restrict__ W1,
    const short* __restrict__ W2p,
    const short* __restrict__ W3p,
    const short* __restrict__ W4p,
    const int*   __restrict__ elist,
    int c0, int ne,
    float*       __restrict__ tpw) {
    __shared__ __align__(16) short h0[64][72];   // padded: 2-way banks only
    __shared__ __align__(16) short h1[64][72];

    const int tid = threadIdx.x;
    const int l   = tid & 63;
    const int w   = tid >> 6;
    const int r16 = l & 15;
    const int g4  = l >> 4;
    const int base = blockIdx.x * 64;
    const int erow = w * 16 + r16;               // this lane's edge row

    // ---- layer 1 (f32 VALU)
    {
        const int pos = base + erow;
        const int e = elist[c0 + ((pos < ne) ? pos : 0)];
        float4 f0 = ((const float4*)edge_feats)[(size_t)e * 2 + 0];
        float4 f1 = ((const float4*)edge_feats)[(size_t)e * 2 + 1];
        float ef[8] = {f0.x, f0.y, f0.z, f0.w, f1.x, f1.y, f1.z, f1.w};
        const int j0 = g4 * 16;
        float acc[16];
        #pragma unroll
        for (int jj = 0; jj < 16; ++jj) acc[jj] = 0.f;
        #pragma unroll
        for (int k = 0; k < 8; ++k) {
            const float* wr = W1 + k * 64 + j0;
            float4 w0 = *(const float4*)(wr + 0);
            float4 w1 = *(const float4*)(wr + 4);
            float4 w2 = *(const float4*)(wr + 8);
            float4 w3 = *(const float4*)(wr + 12);
            const float hk = ef[k];
            acc[0]  = fmaf(hk, w0.x, acc[0]);  acc[1]  = fmaf(hk, w0.y, acc[1]);
            acc[2]  = fmaf(hk, w0.z, acc[2]);  acc[3]  = fmaf(hk, w0.w, acc[3]);
            acc[4]  = fmaf(hk, w1.x, acc[4]);  acc[5]  = fmaf(hk, w1.y, acc[5]);
            acc[6]  = fmaf(hk, w1.z, acc[6]);  acc[7]  = fmaf(hk, w1.w, acc[7]);
            acc[8]  = fmaf(hk, w2.x, acc[8]);  acc[9]  = fmaf(hk, w2.y, acc[9]);
            acc[10] = fmaf(hk, w2.z, acc[10]); acc[11] = fmaf(hk, w2.w, acc[11]);
            acc[12] = fmaf(hk, w3.x, acc[12]); acc[13] = fmaf(hk, w3.y, acc[13]);
            acc[14] = fmaf(hk, w3.z, acc[14]); acc[15] = fmaf(hk, w3.w, acc[15]);
        }
        unsigned pk[8];
        #pragma unroll
        for (int q = 0; q < 8; ++q) {
            unsigned lo = (unsigned short)f2bf(silu(acc[2*q]     * INV_SQRT_RB));
            unsigned hi = (unsigned short)f2bf(silu(acc[2*q + 1] * INV_SQRT_RB));
            pk[q] = lo | (hi << 16);
        }
        uint4 A; A.x = pk[0]; A.y = pk[1]; A.z = pk[2]; A.w = pk[3];
        uint4 B; B.x = pk[4]; B.y = pk[5]; B.z = pk[6]; B.w = pk[7];
        *(uint4*)&h0[erow][j0]     = A;
        *(uint4*)&h0[erow][j0 + 8] = B;
    }

    // ---- layer 2: h0 -> h1
    {
        bf16x8 a0 = *(const bf16x8*)&h0[erow][g4 * 8];
        bf16x8 a1 = *(const bf16x8*)&h0[erow][32 + g4 * 8];
        #pragma unroll
        for (int nt = 0; nt < 4; ++nt) {
            bf16x8 b0 = *(const bf16x8*)(W2p + ((nt * 2 + 0) * 64 + l) * 8);
            bf16x8 b1 = *(const bf16x8*)(W2p + ((nt * 2 + 1) * 64 + l) * 8);
            f32x4 c = {0.f, 0.f, 0.f, 0.f};
            c = __builtin_amdgcn_mfma_f32_16x16x32_bf16(a0, b0, c, 0, 0, 0);
            c = __builtin_amdgcn_mfma_f32_16x16x32_bf16(a1, b1, c, 0, 0, 0);
            #pragma unroll
            for (int r = 0; r < 4; ++r)
                h1[w * 16 + g4 * 4 + r][nt * 16 + r16] = f2bf(silu(c[r]));
        }
    }

    // ---- layer 3: h1 -> h0
    {
        bf16x8 a0 = *(const bf16x8*)&h1[erow][g4 * 8];
        bf16x8 a1 = *(const bf16x8*)&h1[erow][32 + g4 * 8];
        #pragma unroll
        for (int nt = 0; nt < 4; ++nt) {
            bf16x8 b0 = *(const bf16x8*)(W3p + ((nt * 2 + 0) * 64 + l) * 8);
            bf16x8 b1 = *(const bf16x8*)(W3p + ((nt * 2 + 1) * 64 + l) * 8);
            f32x4 c = {0.f, 0.f, 0.f, 0.f};
            c = __builtin_amdgcn_mfma_f32_16x16x32_bf16(a0, b0, c, 0, 0, 0);
            c = __builtin_amdgcn_mfma_f32_16x16x32_bf16(a1, b1, c, 0, 0, 0);
            #pragma unroll
            for (int r = 0; r < 4; ++r)
                h0[w * 16 + g4 * 4 + r][nt * 16 + r16] = f2bf(silu(c[r]));
        }
    }

    // ---- layer 4: h0 @ W4p -> tpw
    {
        bf16x8 a0 = *(const bf16x8*)&h0[erow][g4 * 8];
        bf16x8 a1 = *(const bf16x8*)&h0[erow][32 + g4 * 8];
        const int p0 = base + w * 16 + g4 * 4;
        #pragma unroll 2
        for (int nt = 0; nt < 32; ++nt) {
            bf16x8 b0 = *(const bf16x8*)(W4p + ((nt * 2 + 0) * 64 + l) * 8);
            bf16x8 b1 = *(const bf16x8*)(W4p + ((nt * 2 + 1) * 64 + l) * 8);
            f32x4 c = {0.f, 0.f, 0.f, 0.f};
            c = __builtin_amdgcn_mfma_f32_16x16x32_bf16(a0, b0, c, 0, 0, 0);
            c = __builtin_amdgcn_mfma_f32_16x16x32_bf16(a1, b1, c, 0, 0, 0);
            const int o = nt * 16 + r16;
            #pragma unroll
            for (int r = 0; r < 4; ++r) {
                const int p = p0 + r;
                if (p < ne) tpw[(size_t)p * 512 + o] = c[r];
            }
        }
    }
}

// ---------------- K3: CSR gather per node (chunk-clipped) --------
// msg layout: [s0(128) | s1(128) | v m=0 (256) | m=1 (256) | m=2 (256)]
__global__ __launch_bounds__(128) void k_gather(
    const int*    __restrict__ row,
    const int*    __restrict__ snds,
    const float4* __restrict__ eas,
    const float*  __restrict__ tpw,
    const float*  __restrict__ s_up,
    const float*  __restrict__ v_up,
    float*        __restrict__ msg,
    int c0, int c1, int accum) {
    const int nidx = blockIdx.x;
    const int c = threadIdx.x;      // 128 threads, one channel each
    int beg = row[nidx];
    int end = row[nidx + 1];
    if (beg < c0) beg = c0;
    if (end > c1) end = c1;
    if (accum && beg >= end) return;

    float a0 = 0.f, a1 = 0.f, a2 = 0.f, a3 = 0.f,
          a4 = 0.f, a5 = 0.f, a6 = 0.f, a7 = 0.f;

    #pragma unroll 4
    for (int i = beg; i < end; ++i) {
        const int snd = snds[i];
        const float4 ea = eas[i];
        const float y0 = ea.x, y10 = ea.y, y11 = ea.z, y12 = ea.w;

        const float4 t = *(const float4*)(tpw + (size_t)(i - c0) * 512 + c * 4);
        const float se  = s_up[(size_t)snd * 128 + c];
        const float ve0 = v_up[(size_t)snd * 384 + 3 * c + 0];
        const float ve1 = v_up[(size_t)snd * 384 + 3 * c + 1];
        const float ve2 = v_up[(size_t)snd * 384 + 3 * c + 2];

        a0 = fmaf(C000 * t.x * y0, se, a0);
        const float dvy = ve0 * y10 + ve1 * y11 + ve2 * y12;
        a1 = fmaf(C110 * t.w, dvy, a1);
        const float c011t = C011 * t.y * se;
        a2 = fmaf(c011t, y10, a2);
        a3 = fmaf(c011t, y11, a3);
        a4 = fmaf(c011t, y12, a4);
        const float c101t = C101 * t.z * y0;
        a5 = fmaf(c101t, ve0, a5);
        a6 = fmaf(c101t, ve1, a6);
        a7 = fmaf(c101t, ve2, a7);
    }

    float* m = msg + (size_t)nidx * 1024;
    if (accum) {
        m[c]             += a0;
        m[128 + c]       += a1;
        m[256 + c]       += a2;   // v plane m=0, k = c
        m[512 + c]       += a3;   // v plane m=1
        m[768 + c]       += a4;   // v plane m=2
        m[256 + 128 + c] += a5;   // v plane m=0, k = 128+c
        m[512 + 128 + c] += a6;
        m[768 + 128 + c] += a7;
    } else {
        m[c]             = a0;
        m[128 + c]       = a1;
        m[256 + c]       = a2;
        m[512 + c]       = a3;
        m[768 + c]       = a4;
        m[256 + 128 + c] = a5;
        m[512 + 128 + c] = a6;
        m[768 + 128 + c] = a7;
    }
}

// ---------------- K4: final node linear, MFMA, 8 waves/block ----------------
// Block = 512 threads = 8 waves; wave w: section w&3 (s,v0,v1,v2), nt-half w>>2.
// 16 nodes per block, grid 625. C-mapping identical to k_edge_mfma (verified).
__global__ __launch_bounds__(512) void k_node_out(
    const float* __restrict__ msg,
    const short* __restrict__ Wlsp,
    const short* __restrict__ Wlvp,
    float*       __restrict__ out) {
    const int tid = threadIdx.x;
    const int l   = tid & 63;        // lane
    const int w   = tid >> 6;        // wave 0..7
    const int sec = w & 3;           // 0=s, 1..3=v planes
    const int nth = w >> 2;          // nt half: 0 or 1
    const int r16 = l & 15;
    const int g4  = l >> 4;
    const int n0  = blockIdx.x * 16;
    const float* mrow = msg + (size_t)(n0 + r16) * 1024 + sec * 256;

    // A fragments: 8 k-tiles of this section's K=256
    bf16x8 a[8];
    #pragma unroll
    for (int kt = 0; kt < 8; ++kt) {
        const float* p = mrow + kt * 32 + g4 * 8;
        float4 x0 = *(const float4*)p;
        float4 x1 = *(const float4*)(p + 4);
        bf16x8 t;
        t[0] = f2bf(x0.x); t[1] = f2bf(x0.y); t[2] = f2bf(x0.z); t[3] = f2bf(x0.w);
        t[4] = f2bf(x1.x); t[5] = f2bf(x1.y); t[6] = f2bf(x1.z); t[7] = f2bf(x1.w);
        a[kt] = t;
    }
    const short* Wp = (sec == 0) ? Wlsp : Wlvp;
    #pragma unroll
    for (int ni = 0; ni < 4; ++ni) {
        const int nt = nth * 4 + ni;
        f32x4 c = {0.f, 0.f, 0.f, 0.f};
        #pragma unroll
        for (int kt = 0; kt < 8; ++kt) {
            bf16x8 b = *(const bf16x8*)(Wp + ((nt * 8 + kt) * 64 + l) * 8);
            c = __builtin_amdgcn_mfma_f32_16x16x32_bf16(a[kt], b, c, 0, 0, 0);
        }
        const int d = nt * 16 + r16;
        #pragma unroll
        for (int r = 0; r < 4; ++r) {
            const size_t n = n0 + g4 * 4 + r;
            if (sec == 0) out[n * 512 + d] = c[r];
            else          out[n * 512 + 128 + 3 * d + (sec - 1)] = c[r];
        }
    }
}

extern "C" void kernel_launch(void* const* d_in, const int* in_sizes, int n_in,
                              void* d_out, int out_size, void* d_ws, size_t ws_size,
                              hipStream_t stream) {
    const float* node_feats = (const float*)d_in[1];
    const float* edge_attrs = (const float*)d_in[2];
    const float* edge_feats = (const float*)d_in[3];
    const int*   edge_index = (const int*)d_in[4];
    const float* W_up_s = (const float*)d_in[5];
    const float* W_up_v = (const float*)d_in[6];
    const float* W_mlp1 = (const float*)d_in[7];
    const float* W_mlp2 = (const float*)d_in[8];
    const float* W_mlp3 = (const float*)d_in[9];
    const float* W_mlp4 = (const float*)d_in[10];
    const float* W_lin_s = (const float*)d_in[11];
    const float* W_lin_v = (const float*)d_in[12];

    float* ws     = (float*)d_ws;
    float* s_up   = ws + S_UP_OFF;
    float* v_up   = ws + V_UP_OFF;
    float* msg    = ws + MSG_OFF;
    short* W2p    = (short*)(ws + WP_OFF);   // 4096 shorts
    short* W3p    = W2p + 4096;              // 4096
    short* W4p    = W3p + 4096;              // 32768
    short* Wlsp   = W4p + 32768;             // 32768
    short* Wlvp   = Wlsp + 32768;            // 32768
    int*   row    = (int*)(ws + ROW_OFF);
    int*   elist  = (int*)(ws + ELIST_OFF);
    int*   snds   = (int*)(ws + SNDS_OFF);
    float4* eas   = (float4*)(ws + EAS_OFF);
    float* tpw    = ws + TPW_OFF;
    int*   cnt    = (int*)msg;
    int*   cursor = cnt + N_NODES;
    float* out_f  = (float*)d_out;

    // adaptive chunking from actual ws_size (deterministic across calls)
    size_t total_f = ws_size / 4;
    if (total_f > MAX_TOTAL_F) total_f = MAX_TOTAL_F;
    size_t cap_f = (total_f > TPW_OFF) ? (total_f - TPW_OFF) : 0;
    long long ce = (long long)(cap_f / 512);
    ce &= ~63LL;
    if (ce < 64) ce = 64;
    if (ce > N_EDGES) ce = N_EDGES;
    const int chunkE = (int)ce;
    const int nch = (N_EDGES + chunkE - 1) / chunkE;

    (void)hipMemsetAsync(cnt, 0, 2 * N_NODES * sizeof(int), stream);
    k_pack<<<416, 256, 0, stream>>>(W_mlp2, W_mlp3, W_mlp4, W_lin_s, W_lin_v,
                                    W2p, W3p, W4p, Wlsp, Wlvp);
    k_node_up<<<N_NODES / NPB, 128, 0, stream>>>(node_feats, W_up_s, W_up_v, s_up, v_up);
    k_hist<<<N_EDGES / 256, 256, 0, stream>>>(edge_index, cnt);
    k_scan<<<1, 256, 0, stream>>>(cnt, row, cursor);
    k_scatter<<<N_EDGES / 256, 256, 0, stream>>>(edge_index, cursor, edge_attrs,
                                                 elist, snds, eas);

    for (int ch = 0; ch < nch; ++ch) {
        const int c0 = ch * chunkE;
        const int c1 = (c0 + chunkE < N_EDGES) ? c0 + chunkE : N_EDGES;
        const int ne = c1 - c0;
        k_edge_mfma<<<(ne + 63) / 64, 256, 0, stream>>>(
            edge_feats, W_mlp1, W2p, W3p, W4p, elist, c0, ne, tpw);
        k_gather<<<N_NODES, 128, 0, stream>>>(
            row, snds, eas, tpw, s_up, v_up, msg, c0, c1, ch == 0 ? 0 : 1);
    }
    k_node_out<<<625, 512, 0, stream>>>(msg, Wlsp, Wlvp, out_f);
}

// Round 10
// 292.390 us; speedup vs baseline: 12.2393x; 1.1848x over previous
//
#include <hip/hip_runtime.h>

// MACE node message block. bf16-MFMA edge MLP (bf16 tpw) + CSR gather + MFMA node_out.
// N=10000, E=160000, C=128, RB=8, HID=64.
//
// ws layout (float units):
//   [0 .. 1.28M)        s_up (N,128)
//   [1.28M .. 5.12M)    v_up (N,128,3)
//   [5.12M .. 15.36M)   msg (N,1024) = [s0|s1|v0|v1|v2 planes]; cnt/cursor pre-gather
//   [15.36M .. +53248)  packed bf16 weights: W2p W3p W4p Wlsp Wlvp
//   [15413248 +10001]   row (int)
//   [15423252 +160000]  elist (int)
//   [15583252 +160000]  snds (int)
//   [15743252 +640000]  eas (float4)
//   [16383252 .. )      tpw chunk buffer [pos][512] bf16 (ushort)
// full-E tpw = 164 MB; total ~229 MB < 389.93 MB proven cap -> single chunk.

#define N_NODES 10000
#define N_EDGES 160000

#define S_UP_OFF   0u
#define V_UP_OFF   1280000u
#define MSG_OFF    5120000u
#define WP_OFF     15360000u
#define ROW_OFF    15413248u
#define ELIST_OFF  15423252u
#define SNDS_OFF   15583252u
#define EAS_OFF    15743252u
#define TPW_OFF    16383252u
#define MAX_TOTAL_F 97482772u

typedef __attribute__((ext_vector_type(8))) short bf16x8;
typedef __attribute__((ext_vector_type(4))) float f32x4;

__device__ __forceinline__ float silu(float x) {
    return x / (1.0f + __expf(-x));
}
__device__ __forceinline__ short f2bf(float x) {
    unsigned u = __float_as_uint(x);
    unsigned r = (u + 0x7FFFu + ((u >> 16) & 1u)) >> 16;
    return (short)r;
}
__device__ __forceinline__ float bf2f(unsigned h) {
    return __uint_as_float(h << 16);
}

constexpr float INV_SQRT_C  = 0.08838834764831845f;
constexpr float INV_SQRT_RB = 0.35355339059327373f;
constexpr float INV_SQRT_H  = 0.125f;
constexpr float OUT_SCALE   = 0.0625f * 0.0625f;      // 1/sqrt(256) / AVG_NEIGH
constexpr float C000 = 0.7071067811865476f;
constexpr float C110 = 0.4082482904638631f;
constexpr float C011 = 0.7071067811865476f;
constexpr float C101 = 0.7071067811865476f;

// ---------------- K0: pack weights into bf16 MFMA fragment order ----------
__global__ void k_pack(const float* __restrict__ W2, const float* __restrict__ W3,
                       const float* __restrict__ W4,
                       const float* __restrict__ Wls, const float* __restrict__ Wlv,
                       short* __restrict__ W2p, short* __restrict__ W3p,
                       short* __restrict__ W4p,
                       short* __restrict__ Wlsp, short* __restrict__ Wlvp) {
    int idx = blockIdx.x * 256 + threadIdx.x;   // 106496 total
    if (idx < 4096) {
        int i2 = idx;
        int e = i2 & 7, l = (i2 >> 3) & 63, kt = (i2 >> 9) & 1, nt = i2 >> 10;
        int k = kt * 32 + (l >> 4) * 8 + e;
        int col = nt * 16 + (l & 15);
        W2p[i2] = f2bf(W2[k * 64 + col] * INV_SQRT_H);
    } else if (idx < 8192) {
        int i2 = idx - 4096;
        int e = i2 & 7, l = (i2 >> 3) & 63, kt = (i2 >> 9) & 1, nt = i2 >> 10;
        int k = kt * 32 + (l >> 4) * 8 + e;
        int col = nt * 16 + (l & 15);
        W3p[i2] = f2bf(W3[k * 64 + col] * INV_SQRT_H);
    } else if (idx < 40960) {
        int i2 = idx - 8192;
        int e = i2 & 7, l = (i2 >> 3) & 63, kt = (i2 >> 9) & 1, nt = i2 >> 10; // nt 0..31
        int k = kt * 32 + (l >> 4) * 8 + e;
        int o = nt * 16 + (l & 15);      // o = c*4 + a
        int c = o >> 2, a = o & 3;
        W4p[i2] = f2bf(W4[k * 512 + a * 128 + c] * INV_SQRT_H);
    } else if (idx < 73728) {
        int i2 = idx - 40960;
        int e = i2 & 7, l = (i2 >> 3) & 63, kt = (i2 >> 9) & 7, nt = (i2 >> 12) & 7;
        int k = kt * 32 + (l >> 4) * 8 + e;
        int d = nt * 16 + (l & 15);
        Wlsp[i2] = f2bf(Wls[k * 128 + d] * OUT_SCALE);
    } else if (idx < 106496) {
        int i2 = idx - 73728;
        int e = i2 & 7, l = (i2 >> 3) & 63, kt = (i2 >> 9) & 7, nt = (i2 >> 12) & 7;
        int k = kt * 32 + (l >> 4) * 8 + e;
        int d = nt * 16 + (l & 15);
        Wlvp[i2] = f2bf(Wlv[k * 128 + d] * OUT_SCALE);
    }
}

// ---------------- K1: node up-projection (f32, unchanged) ----------------
#define NPB 8
__global__ void k_node_up(const float* __restrict__ nf,
                          const float* __restrict__ Wus,
                          const float* __restrict__ Wuv,
                          float* __restrict__ s_up,
                          float* __restrict__ v_up) {
    __shared__ float lds[NPB][512];
    const int n0 = blockIdx.x * NPB;
    const int tid = threadIdx.x;  // 128 threads

    const float4* src = (const float4*)(nf + (size_t)n0 * 512);
    float4* dst = (float4*)(&lds[0][0]);
    #pragma unroll
    for (int i = 0; i < NPB; ++i) dst[tid + 128 * i] = src[tid + 128 * i];
    __syncthreads();

    const int d = tid;
    float acc_s[NPB];
    float acc_v[NPB][3];
    #pragma unroll
    for (int p = 0; p < NPB; ++p) {
        acc_s[p] = 0.f; acc_v[p][0] = 0.f; acc_v[p][1] = 0.f; acc_v[p][2] = 0.f;
    }
    for (int c = 0; c < 128; ++c) {
        float ws = Wus[c * 128 + d];
        float wv = Wuv[c * 128 + d];
        #pragma unroll
        for (int p = 0; p < NPB; ++p) {
            acc_s[p]    = fmaf(lds[p][c],             ws, acc_s[p]);
            acc_v[p][0] = fmaf(lds[p][128 + 3*c + 0], wv, acc_v[p][0]);
            acc_v[p][1] = fmaf(lds[p][128 + 3*c + 1], wv, acc_v[p][1]);
            acc_v[p][2] = fmaf(lds[p][128 + 3*c + 2], wv, acc_v[p][2]);
        }
    }
    #pragma unroll
    for (int p = 0; p < NPB; ++p) {
        int n = n0 + p;
        s_up[(size_t)n * 128 + d]         = acc_s[p]    * INV_SQRT_C;
        v_up[(size_t)n * 384 + 3*d + 0]   = acc_v[p][0] * INV_SQRT_C;
        v_up[(size_t)n * 384 + 3*d + 1]   = acc_v[p][1] * INV_SQRT_C;
        v_up[(size_t)n * 384 + 3*d + 2]   = acc_v[p][2] * INV_SQRT_C;
    }
}

// ---------------- CSR build ----------------
__global__ void k_hist(const int* __restrict__ ei, int* __restrict__ cnt) {
    int e = blockIdx.x * 256 + threadIdx.x;
    if (e < N_EDGES) atomicAdd(&cnt[ei[N_EDGES + e]], 1);
}

__global__ void k_scan(const int* __restrict__ cnt, int* __restrict__ row,
                       int* __restrict__ cursor) {
    __shared__ int part[256];
    const int t = threadIdx.x;
    const int base = t * 40;
    int s = 0;
    for (int i = 0; i < 40; ++i) {
        int idx = base + i;
        s += (idx < N_NODES) ? cnt[idx] : 0;
    }
    part[t] = s;
    __syncthreads();
    for (int off = 1; off < 256; off <<= 1) {
        int v = (t >= off) ? part[t - off] : 0;
        __syncthreads();
        part[t] += v;
        __syncthreads();
    }
    int run = part[t] - s;   // exclusive prefix
    for (int i = 0; i < 40; ++i) {
        int idx = base + i;
        if (idx < N_NODES) {
            row[idx] = run;
            cursor[idx] = run;
            run += cnt[idx];
        }
    }
    if (t == 255) row[N_NODES] = part[255];
}

__global__ void k_scatter(const int* __restrict__ ei, int* __restrict__ cursor,
                          const float* __restrict__ edge_attrs,
                          int* __restrict__ elist, int* __restrict__ snds,
                          float4* __restrict__ eas) {
    int e = blockIdx.x * 256 + threadIdx.x;
    if (e < N_EDGES) {
        int snd = ei[e];
        int r = ei[N_EDGES + e];
        int pos = atomicAdd(&cursor[r], 1);
        elist[pos] = e;
        snds[pos] = snd;
        eas[pos] = ((const float4*)edge_attrs)[e];
    }
}

// ---------------- K2: bf16-MFMA edge MLP -> tpw16[pos][512] bf16 ------------
// Layer 4 uses SWAPPED operands: mfma(W4frag, hfrag) so C rows = outputs o,
// cols = edges; lane l then holds t0..t3 of channel c = nt*4+(l>>4) for edge
// w*16+(l&15), packed to 4 bf16 and stored as one 8-byte write.
__global__ __launch_bounds__(256) void k_edge_mfma(
    const float* __restrict__ edge_feats,
    const float* __restrict__ W1,
    const short* __restrict__ W2p,
    const short* __restrict__ W3p,
    const short* __restrict__ W4p,
    const int*   __restrict__ elist,
    int c0, int ne,
    unsigned short* __restrict__ tpw16) {
    __shared__ __align__(16) short h0[64][72];   // padded: 2-way banks only
    __shared__ __align__(16) short h1[64][72];

    const int tid = threadIdx.x;
    const int l   = tid & 63;
    const int w   = tid >> 6;
    const int r16 = l & 15;
    const int g4  = l >> 4;
    const int base = blockIdx.x * 64;
    const int erow = w * 16 + r16;               // this lane's edge row

    // ---- layer 1 (f32 VALU)
    {
        const int pos = base + erow;
        const int e = elist[c0 + ((pos < ne) ? pos : 0)];
        float4 f0 = ((const float4*)edge_feats)[(size_t)e * 2 + 0];
        float4 f1 = ((const float4*)edge_feats)[(size_t)e * 2 + 1];
        float ef[8] = {f0.x, f0.y, f0.z, f0.w, f1.x, f1.y, f1.z, f1.w};
        const int j0 = g4 * 16;
        float acc[16];
        #pragma unroll
        for (int jj = 0; jj < 16; ++jj) acc[jj] = 0.f;
        #pragma unroll
        for (int k = 0; k < 8; ++k) {
            const float* wr = W1 + k * 64 + j0;
            float4 w0 = *(const float4*)(wr + 0);
            float4 w1 = *(const float4*)(wr + 4);
            float4 w2 = *(const float4*)(wr + 8);
            float4 w3 = *(const float4*)(wr + 12);
            const float hk = ef[k];
            acc[0]  = fmaf(hk, w0.x, acc[0]);  acc[1]  = fmaf(hk, w0.y, acc[1]);
            acc[2]  = fmaf(hk, w0.z, acc[2]);  acc[3]  = fmaf(hk, w0.w, acc[3]);
            acc[4]  = fmaf(hk, w1.x, acc[4]);  acc[5]  = fmaf(hk, w1.y, acc[5]);
            acc[6]  = fmaf(hk, w1.z, acc[6]);  acc[7]  = fmaf(hk, w1.w, acc[7]);
            acc[8]  = fmaf(hk, w2.x, acc[8]);  acc[9]  = fmaf(hk, w2.y, acc[9]);
            acc[10] = fmaf(hk, w2.z, acc[10]); acc[11] = fmaf(hk, w2.w, acc[11]);
            acc[12] = fmaf(hk, w3.x, acc[12]); acc[13] = fmaf(hk, w3.y, acc[13]);
            acc[14] = fmaf(hk, w3.z, acc[14]); acc[15] = fmaf(hk, w3.w, acc[15]);
        }
        unsigned pk[8];
        #pragma unroll
        for (int q = 0; q < 8; ++q) {
            unsigned lo = (unsigned short)f2bf(silu(acc[2*q]     * INV_SQRT_RB));
            unsigned hi = (unsigned short)f2bf(silu(acc[2*q + 1] * INV_SQRT_RB));
            pk[q] = lo | (hi << 16);
        }
        uint4 A; A.x = pk[0]; A.y = pk[1]; A.z = pk[2]; A.w = pk[3];
        uint4 B; B.x = pk[4]; B.y = pk[5]; B.z = pk[6]; B.w = pk[7];
        *(uint4*)&h0[erow][j0]     = A;
        *(uint4*)&h0[erow][j0 + 8] = B;
    }

    // ---- layer 2: h0 -> h1
    {
        bf16x8 a0 = *(const bf16x8*)&h0[erow][g4 * 8];
        bf16x8 a1 = *(const bf16x8*)&h0[erow][32 + g4 * 8];
        #pragma unroll
        for (int nt = 0; nt < 4; ++nt) {
            bf16x8 b0 = *(const bf16x8*)(W2p + ((nt * 2 + 0) * 64 + l) * 8);
            bf16x8 b1 = *(const bf16x8*)(W2p + ((nt * 2 + 1) * 64 + l) * 8);
            f32x4 c = {0.f, 0.f, 0.f, 0.f};
            c = __builtin_amdgcn_mfma_f32_16x16x32_bf16(a0, b0, c, 0, 0, 0);
            c = __builtin_amdgcn_mfma_f32_16x16x32_bf16(a1, b1, c, 0, 0, 0);
            #pragma unroll
            for (int r = 0; r < 4; ++r)
                h1[w * 16 + g4 * 4 + r][nt * 16 + r16] = f2bf(silu(c[r]));
        }
    }

    // ---- layer 3: h1 -> h0
    {
        bf16x8 a0 = *(const bf16x8*)&h1[erow][g4 * 8];
        bf16x8 a1 = *(const bf16x8*)&h1[erow][32 + g4 * 8];
        #pragma unroll
        for (int nt = 0; nt < 4; ++nt) {
            bf16x8 b0 = *(const bf16x8*)(W3p + ((nt * 2 + 0) * 64 + l) * 8);
            bf16x8 b1 = *(const bf16x8*)(W3p + ((nt * 2 + 1) * 64 + l) * 8);
            f32x4 c = {0.f, 0.f, 0.f, 0.f};
            c = __builtin_amdgcn_mfma_f32_16x16x32_bf16(a0, b0, c, 0, 0, 0);
            c = __builtin_amdgcn_mfma_f32_16x16x32_bf16(a1, b1, c, 0, 0, 0);
            #pragma unroll
            for (int r = 0; r < 4; ++r)
                h0[w * 16 + g4 * 4 + r][nt * 16 + r16] = f2bf(silu(c[r]));
        }
    }

    // ---- layer 4 (swapped operands): per nt, lane holds channel nt*4+g4,
    // edge w*16+r16, values t0..t3 -> one 8B bf16x4 store.
    {
        bf16x8 ha0 = *(const bf16x8*)&h0[erow][g4 * 8];       // B-operand role
        bf16x8 ha1 = *(const bf16x8*)&h0[erow][32 + g4 * 8];
        const int p = base + erow;                            // chunk-rel position
        const bool valid = (p < ne);
        unsigned short* tp = tpw16 + (size_t)p * 512;
        #pragma unroll 4
        for (int nt = 0; nt < 32; ++nt) {
            bf16x8 w0 = *(const bf16x8*)(W4p + ((nt * 2 + 0) * 64 + l) * 8);  // A role
            bf16x8 w1 = *(const bf16x8*)(W4p + ((nt * 2 + 1) * 64 + l) * 8);
            f32x4 c = {0.f, 0.f, 0.f, 0.f};
            c = __builtin_amdgcn_mfma_f32_16x16x32_bf16(w0, ha0, c, 0, 0, 0);
            c = __builtin_amdgcn_mfma_f32_16x16x32_bf16(w1, ha1, c, 0, 0, 0);
            if (valid) {
                const int ch = nt * 4 + g4;
                uint2 u;
                u.x = (unsigned)(unsigned short)f2bf(c[0]) |
                      ((unsigned)(unsigned short)f2bf(c[1]) << 16);
                u.y = (unsigned)(unsigned short)f2bf(c[2]) |
                      ((unsigned)(unsigned short)f2bf(c[3]) << 16);
                *(uint2*)(tp + ch * 4) = u;
            }
        }
    }
}

// ---------------- K3: CSR gather per node (chunk-clipped) --------
// msg layout: [s0(128) | s1(128) | v m=0 (256) | m=1 (256) | m=2 (256)]
__global__ __launch_bounds__(128) void k_gather(
    const int*    __restrict__ row,
    const int*    __restrict__ snds,
    const float4* __restrict__ eas,
    const unsigned short* __restrict__ tpw16,
    const float*  __restrict__ s_up,
    const float*  __restrict__ v_up,
    float*        __restrict__ msg,
    int c0, int c1, int accum) {
    const int nidx = blockIdx.x;
    const int c = threadIdx.x;      // 128 threads, one channel each
    int beg = row[nidx];
    int end = row[nidx + 1];
    if (beg < c0) beg = c0;
    if (end > c1) end = c1;
    if (accum && beg >= end) return;

    float a0 = 0.f, a1 = 0.f, a2 = 0.f, a3 = 0.f,
          a4 = 0.f, a5 = 0.f, a6 = 0.f, a7 = 0.f;

    #pragma unroll 4
    for (int i = beg; i < end; ++i) {
        const int snd = snds[i];
        const float4 ea = eas[i];
        const float y0 = ea.x, y10 = ea.y, y11 = ea.z, y12 = ea.w;

        const uint2 u = *(const uint2*)(tpw16 + (size_t)(i - c0) * 512 + c * 4);
        const float t0 = bf2f(u.x & 0xffffu);
        const float t1 = bf2f(u.x >> 16);
        const float t2 = bf2f(u.y & 0xffffu);
        const float t3 = bf2f(u.y >> 16);
        const float se  = s_up[(size_t)snd * 128 + c];
        const float ve0 = v_up[(size_t)snd * 384 + 3 * c + 0];
        const float ve1 = v_up[(size_t)snd * 384 + 3 * c + 1];
        const float ve2 = v_up[(size_t)snd * 384 + 3 * c + 2];

        a0 = fmaf(C000 * t0 * y0, se, a0);
        const float dvy = ve0 * y10 + ve1 * y11 + ve2 * y12;
        a1 = fmaf(C110 * t3, dvy, a1);
        const float c011t = C011 * t1 * se;
        a2 = fmaf(c011t, y10, a2);
        a3 = fmaf(c011t, y11, a3);
        a4 = fmaf(c011t, y12, a4);
        const float c101t = C101 * t2 * y0;
        a5 = fmaf(c101t, ve0, a5);
        a6 = fmaf(c101t, ve1, a6);
        a7 = fmaf(c101t, ve2, a7);
    }

    float* m = msg + (size_t)nidx * 1024;
    if (accum) {
        m[c]             += a0;
        m[128 + c]       += a1;
        m[256 + c]       += a2;   // v plane m=0, k = c
        m[512 + c]       += a3;   // v plane m=1
        m[768 + c]       += a4;   // v plane m=2
        m[256 + 128 + c] += a5;   // v plane m=0, k = 128+c
        m[512 + 128 + c] += a6;
        m[768 + 128 + c] += a7;
    } else {
        m[c]             = a0;
        m[128 + c]       = a1;
        m[256 + c]       = a2;
        m[512 + c]       = a3;
        m[768 + c]       = a4;
        m[256 + 128 + c] = a5;
        m[512 + 128 + c] = a6;
        m[768 + 128 + c] = a7;
    }
}

// ---------------- K4: final node linear, MFMA, 8 waves/block ----------------
__global__ __launch_bounds__(512) void k_node_out(
    const float* __restrict__ msg,
    const short* __restrict__ Wlsp,
    const short* __restrict__ Wlvp,
    float*       __restrict__ out) {
    const int tid = threadIdx.x;
    const int l   = tid & 63;        // lane
    const int w   = tid >> 6;        // wave 0..7
    const int sec = w & 3;           // 0=s, 1..3=v planes
    const int nth = w >> 2;          // nt half: 0 or 1
    const int r16 = l & 15;
    const int g4  = l >> 4;
    const int n0  = blockIdx.x * 16;
    const float* mrow = msg + (size_t)(n0 + r16) * 1024 + sec * 256;

    bf16x8 a[8];
    #pragma unroll
    for (int kt = 0; kt < 8; ++kt) {
        const float* p = mrow + kt * 32 + g4 * 8;
        float4 x0 = *(const float4*)p;
        float4 x1 = *(const float4*)(p + 4);
        bf16x8 t;
        t[0] = f2bf(x0.x); t[1] = f2bf(x0.y); t[2] = f2bf(x0.z); t[3] = f2bf(x0.w);
        t[4] = f2bf(x1.x); t[5] = f2bf(x1.y); t[6] = f2bf(x1.z); t[7] = f2bf(x1.w);
        a[kt] = t;
    }
    const short* Wp = (sec == 0) ? Wlsp : Wlvp;
    #pragma unroll
    for (int ni = 0; ni < 4; ++ni) {
        const int nt = nth * 4 + ni;
        f32x4 c = {0.f, 0.f, 0.f, 0.f};
        #pragma unroll
        for (int kt = 0; kt < 8; ++kt) {
            bf16x8 b = *(const bf16x8*)(Wp + ((nt * 8 + kt) * 64 + l) * 8);
            c = __builtin_amdgcn_mfma_f32_16x16x32_bf16(a[kt], b, c, 0, 0, 0);
        }
        const int d = nt * 16 + r16;
        #pragma unroll
        for (int r = 0; r < 4; ++r) {
            const size_t n = n0 + g4 * 4 + r;
            if (sec == 0) out[n * 512 + d] = c[r];
            else          out[n * 512 + 128 + 3 * d + (sec - 1)] = c[r];
        }
    }
}

extern "C" void kernel_launch(void* const* d_in, const int* in_sizes, int n_in,
                              void* d_out, int out_size, void* d_ws, size_t ws_size,
                              hipStream_t stream) {
    const float* node_feats = (const float*)d_in[1];
    const float* edge_attrs = (const float*)d_in[2];
    const float* edge_feats = (const float*)d_in[3];
    const int*   edge_index = (const int*)d_in[4];
    const float* W_up_s = (const float*)d_in[5];
    const float* W_up_v = (const float*)d_in[6];
    const float* W_mlp1 = (const float*)d_in[7];
    const float* W_mlp2 = (const float*)d_in[8];
    const float* W_mlp3 = (const float*)d_in[9];
    const float* W_mlp4 = (const float*)d_in[10];
    const float* W_lin_s = (const float*)d_in[11];
    const float* W_lin_v = (const float*)d_in[12];

    float* ws     = (float*)d_ws;
    float* s_up   = ws + S_UP_OFF;
    float* v_up   = ws + V_UP_OFF;
    float* msg    = ws + MSG_OFF;
    short* W2p    = (short*)(ws + WP_OFF);   // 4096 shorts
    short* W3p    = W2p + 4096;              // 4096
    short* W4p    = W3p + 4096;              // 32768
    short* Wlsp   = W4p + 32768;             // 32768
    short* Wlvp   = Wlsp + 32768;            // 32768
    int*   row    = (int*)(ws + ROW_OFF);
    int*   elist  = (int*)(ws + ELIST_OFF);
    int*   snds   = (int*)(ws + SNDS_OFF);
    float4* eas   = (float4*)(ws + EAS_OFF);
    unsigned short* tpw16 = (unsigned short*)(ws + TPW_OFF);
    int*   cnt    = (int*)msg;
    int*   cursor = cnt + N_NODES;
    float* out_f  = (float*)d_out;

    // adaptive chunking from actual ws_size (deterministic across calls)
    size_t total_f = ws_size / 4;
    if (total_f > MAX_TOTAL_F) total_f = MAX_TOTAL_F;
    size_t cap_f = (total_f > TPW_OFF) ? (total_f - TPW_OFF) : 0;
    long long ce = (long long)(cap_f / 256);   // 512 bf16 = 256 floats per edge
    ce &= ~63LL;
    if (ce < 64) ce = 64;
    if (ce > N_EDGES) ce = N_EDGES;
    const int chunkE = (int)ce;                 // = N_EDGES (single chunk) at ~390MB ws
    const int nch = (N_EDGES + chunkE - 1) / chunkE;

    (void)hipMemsetAsync(cnt, 0, 2 * N_NODES * sizeof(int), stream);
    k_pack<<<416, 256, 0, stream>>>(W_mlp2, W_mlp3, W_mlp4, W_lin_s, W_lin_v,
                                    W2p, W3p, W4p, Wlsp, Wlvp);
    k_node_up<<<N_NODES / NPB, 128, 0, stream>>>(node_feats, W_up_s, W_up_v, s_up, v_up);
    k_hist<<<N_EDGES / 256, 256, 0, stream>>>(edge_index, cnt);
    k_scan<<<1, 256, 0, stream>>>(cnt, row, cursor);
    k_scatter<<<N_EDGES / 256, 256, 0, stream>>>(edge_index, cursor, edge_attrs,
                                                 elist, snds, eas);

    for (int ch = 0; ch < nch; ++ch) {
        const int c0 = ch * chunkE;
        const int c1 = (c0 + chunkE < N_EDGES) ? c0 + chunkE : N_EDGES;
        const int ne = c1 - c0;
        k_edge_mfma<<<(ne + 63) / 64, 256, 0, stream>>>(
            edge_feats, W_mlp1, W2p, W3p, W4p, elist, c0, ne, tpw16);
        k_gather<<<N_NODES, 128, 0, stream>>>(
            row, snds, eas, tpw16, s_up, v_up, msg, c0, c1, ch == 0 ? 0 : 1);
    }
    k_node_out<<<625, 512, 0, stream>>>(msg, Wlsp, Wlvp, out_f);
}

// Round 11
// 275.638 us; speedup vs baseline: 12.9832x; 1.0608x over previous
//
#include <hip/hip_runtime.h>

// MACE node message block. bf16-MFMA edge MLP (bf16 tpw, LDS-staged coalesced
// stores) + CSR gather + MFMA node_out.
// N=10000, E=160000, C=128, RB=8, HID=64.
//
// ws layout (float units):
//   [0 .. 1.28M)        s_up (N,128)
//   [1.28M .. 5.12M)    v_up (N,128,3)
//   [5.12M .. 15.36M)   msg (N,1024) = [s0|s1|v0|v1|v2 planes]; cnt/cursor pre-gather
//   [15.36M .. +53248)  packed bf16 weights: W2p W3p W4p Wlsp Wlvp
//   [15413248 +10001]   row (int)
//   [15423252 +160000]  elist (int)
//   [15583252 +160000]  snds (int)
//   [15743252 +640000]  eas (float4)
//   [16383252 .. )      tpw chunk buffer [pos][512] bf16 (ushort)
// full-E tpw = 164 MB; total ~229 MB < 389.93 MB proven cap -> single chunk.

#define N_NODES 10000
#define N_EDGES 160000

#define S_UP_OFF   0u
#define V_UP_OFF   1280000u
#define MSG_OFF    5120000u
#define WP_OFF     15360000u
#define ROW_OFF    15413248u
#define ELIST_OFF  15423252u
#define SNDS_OFF   15583252u
#define EAS_OFF    15743252u
#define TPW_OFF    16383252u
#define MAX_TOTAL_F 97482772u

typedef __attribute__((ext_vector_type(8))) short bf16x8;
typedef __attribute__((ext_vector_type(4))) float f32x4;

__device__ __forceinline__ float silu(float x) {
    return x / (1.0f + __expf(-x));
}
__device__ __forceinline__ short f2bf(float x) {
    unsigned u = __float_as_uint(x);
    unsigned r = (u + 0x7FFFu + ((u >> 16) & 1u)) >> 16;
    return (short)r;
}
__device__ __forceinline__ unsigned pk2bf(float lo, float hi) {
    return (unsigned)(unsigned short)f2bf(lo) |
           ((unsigned)(unsigned short)f2bf(hi) << 16);
}
__device__ __forceinline__ float bf2f(unsigned h) {
    return __uint_as_float(h << 16);
}

constexpr float INV_SQRT_C  = 0.08838834764831845f;
constexpr float INV_SQRT_RB = 0.35355339059327373f;
constexpr float INV_SQRT_H  = 0.125f;
constexpr float OUT_SCALE   = 0.0625f * 0.0625f;      // 1/sqrt(256) / AVG_NEIGH
constexpr float C000 = 0.7071067811865476f;
constexpr float C110 = 0.4082482904638631f;
constexpr float C011 = 0.7071067811865476f;
constexpr float C101 = 0.7071067811865476f;

// ---------------- K0: pack weights into bf16 MFMA fragment order ----------
__global__ void k_pack(const float* __restrict__ W2, const float* __restrict__ W3,
                       const float* __restrict__ W4,
                       const float* __restrict__ Wls, const float* __restrict__ Wlv,
                       short* __restrict__ W2p, short* __restrict__ W3p,
                       short* __restrict__ W4p,
                       short* __restrict__ Wlsp, short* __restrict__ Wlvp) {
    int idx = blockIdx.x * 256 + threadIdx.x;   // 106496 total
    if (idx < 4096) {
        int i2 = idx;
        int e = i2 & 7, l = (i2 >> 3) & 63, kt = (i2 >> 9) & 1, nt = i2 >> 10;
        int k = kt * 32 + (l >> 4) * 8 + e;
        int col = nt * 16 + (l & 15);
        W2p[i2] = f2bf(W2[k * 64 + col] * INV_SQRT_H);
    } else if (idx < 8192) {
        int i2 = idx - 4096;
        int e = i2 & 7, l = (i2 >> 3) & 63, kt = (i2 >> 9) & 1, nt = i2 >> 10;
        int k = kt * 32 + (l >> 4) * 8 + e;
        int col = nt * 16 + (l & 15);
        W3p[i2] = f2bf(W3[k * 64 + col] * INV_SQRT_H);
    } else if (idx < 40960) {
        int i2 = idx - 8192;
        int e = i2 & 7, l = (i2 >> 3) & 63, kt = (i2 >> 9) & 1, nt = i2 >> 10; // nt 0..31
        int k = kt * 32 + (l >> 4) * 8 + e;
        int o = nt * 16 + (l & 15);      // o = c*4 + a
        int c = o >> 2, a = o & 3;
        W4p[i2] = f2bf(W4[k * 512 + a * 128 + c] * INV_SQRT_H);
    } else if (idx < 73728) {
        int i2 = idx - 40960;
        int e = i2 & 7, l = (i2 >> 3) & 63, kt = (i2 >> 9) & 7, nt = (i2 >> 12) & 7;
        int k = kt * 32 + (l >> 4) * 8 + e;
        int d = nt * 16 + (l & 15);
        Wlsp[i2] = f2bf(Wls[k * 128 + d] * OUT_SCALE);
    } else if (idx < 106496) {
        int i2 = idx - 73728;
        int e = i2 & 7, l = (i2 >> 3) & 63, kt = (i2 >> 9) & 7, nt = (i2 >> 12) & 7;
        int k = kt * 32 + (l >> 4) * 8 + e;
        int d = nt * 16 + (l & 15);
        Wlvp[i2] = f2bf(Wlv[k * 128 + d] * OUT_SCALE);
    }
}

// ---------------- K1: node up-projection (f32, unchanged) ----------------
#define NPB 8
__global__ void k_node_up(const float* __restrict__ nf,
                          const float* __restrict__ Wus,
                          const float* __restrict__ Wuv,
                          float* __restrict__ s_up,
                          float* __restrict__ v_up) {
    __shared__ float lds[NPB][512];
    const int n0 = blockIdx.x * NPB;
    const int tid = threadIdx.x;  // 128 threads

    const float4* src = (const float4*)(nf + (size_t)n0 * 512);
    float4* dst = (float4*)(&lds[0][0]);
    #pragma unroll
    for (int i = 0; i < NPB; ++i) dst[tid + 128 * i] = src[tid + 128 * i];
    __syncthreads();

    const int d = tid;
    float acc_s[NPB];
    float acc_v[NPB][3];
    #pragma unroll
    for (int p = 0; p < NPB; ++p) {
        acc_s[p] = 0.f; acc_v[p][0] = 0.f; acc_v[p][1] = 0.f; acc_v[p][2] = 0.f;
    }
    for (int c = 0; c < 128; ++c) {
        float ws = Wus[c * 128 + d];
        float wv = Wuv[c * 128 + d];
        #pragma unroll
        for (int p = 0; p < NPB; ++p) {
            acc_s[p]    = fmaf(lds[p][c],             ws, acc_s[p]);
            acc_v[p][0] = fmaf(lds[p][128 + 3*c + 0], wv, acc_v[p][0]);
            acc_v[p][1] = fmaf(lds[p][128 + 3*c + 1], wv, acc_v[p][1]);
            acc_v[p][2] = fmaf(lds[p][128 + 3*c + 2], wv, acc_v[p][2]);
        }
    }
    #pragma unroll
    for (int p = 0; p < NPB; ++p) {
        int n = n0 + p;
        s_up[(size_t)n * 128 + d]         = acc_s[p]    * INV_SQRT_C;
        v_up[(size_t)n * 384 + 3*d + 0]   = acc_v[p][0] * INV_SQRT_C;
        v_up[(size_t)n * 384 + 3*d + 1]   = acc_v[p][1] * INV_SQRT_C;
        v_up[(size_t)n * 384 + 3*d + 2]   = acc_v[p][2] * INV_SQRT_C;
    }
}

// ---------------- CSR build ----------------
__global__ void k_hist(const int* __restrict__ ei, int* __restrict__ cnt) {
    int e = blockIdx.x * 256 + threadIdx.x;
    if (e < N_EDGES) atomicAdd(&cnt[ei[N_EDGES + e]], 1);
}

__global__ void k_scan(const int* __restrict__ cnt, int* __restrict__ row,
                       int* __restrict__ cursor) {
    __shared__ int part[256];
    const int t = threadIdx.x;
    const int base = t * 40;
    int s = 0;
    for (int i = 0; i < 40; ++i) {
        int idx = base + i;
        s += (idx < N_NODES) ? cnt[idx] : 0;
    }
    part[t] = s;
    __syncthreads();
    for (int off = 1; off < 256; off <<= 1) {
        int v = (t >= off) ? part[t - off] : 0;
        __syncthreads();
        part[t] += v;
        __syncthreads();
    }
    int run = part[t] - s;   // exclusive prefix
    for (int i = 0; i < 40; ++i) {
        int idx = base + i;
        if (idx < N_NODES) {
            row[idx] = run;
            cursor[idx] = run;
            run += cnt[idx];
        }
    }
    if (t == 255) row[N_NODES] = part[255];
}

__global__ void k_scatter(const int* __restrict__ ei, int* __restrict__ cursor,
                          const float* __restrict__ edge_attrs,
                          int* __restrict__ elist, int* __restrict__ snds,
                          float4* __restrict__ eas) {
    int e = blockIdx.x * 256 + threadIdx.x;
    if (e < N_EDGES) {
        int snd = ei[e];
        int r = ei[N_EDGES + e];
        int pos = atomicAdd(&cursor[r], 1);
        elist[pos] = e;
        snds[pos] = snd;
        eas[pos] = ((const float4*)edge_attrs)[e];
    }
}

// ---------------- K2: bf16-MFMA edge MLP -> tpw16[pos][512] bf16 ------------
// Layer 4 swapped operands (mfma(W4frag, hfrag)); results staged per-wave in
// LDS and re-read transposed so each wave stores full 64B lines per edge.
__global__ __launch_bounds__(256) void k_edge_mfma(
    const float* __restrict__ edge_feats,
    const float* __restrict__ W1,
    const short* __restrict__ W2p,
    const short* __restrict__ W3p,
    const short* __restrict__ W4p,
    const int*   __restrict__ elist,
    int c0, int ne,
    unsigned short* __restrict__ tpw16) {
    __shared__ __align__(16) short h0[64][72];   // padded: 2-way banks only
    __shared__ __align__(16) short h1[64][72];
    __shared__ __align__(16) uint2 stg[4][8][17]; // [wave][ch_local][edge+pad]

    const int tid = threadIdx.x;
    const int l   = tid & 63;
    const int w   = tid >> 6;
    const int r16 = l & 15;
    const int g4  = l >> 4;
    const int base = blockIdx.x * 64;
    const int erow = w * 16 + r16;               // this lane's edge row

    // ---- layer 1 (f32 VALU)
    {
        const int pos = base + erow;
        const int e = elist[c0 + ((pos < ne) ? pos : 0)];
        float4 f0 = ((const float4*)edge_feats)[(size_t)e * 2 + 0];
        float4 f1 = ((const float4*)edge_feats)[(size_t)e * 2 + 1];
        float ef[8] = {f0.x, f0.y, f0.z, f0.w, f1.x, f1.y, f1.z, f1.w};
        const int j0 = g4 * 16;
        float acc[16];
        #pragma unroll
        for (int jj = 0; jj < 16; ++jj) acc[jj] = 0.f;
        #pragma unroll
        for (int k = 0; k < 8; ++k) {
            const float* wr = W1 + k * 64 + j0;
            float4 w0 = *(const float4*)(wr + 0);
            float4 w1 = *(const float4*)(wr + 4);
            float4 w2 = *(const float4*)(wr + 8);
            float4 w3 = *(const float4*)(wr + 12);
            const float hk = ef[k];
            acc[0]  = fmaf(hk, w0.x, acc[0]);  acc[1]  = fmaf(hk, w0.y, acc[1]);
            acc[2]  = fmaf(hk, w0.z, acc[2]);  acc[3]  = fmaf(hk, w0.w, acc[3]);
            acc[4]  = fmaf(hk, w1.x, acc[4]);  acc[5]  = fmaf(hk, w1.y, acc[5]);
            acc[6]  = fmaf(hk, w1.z, acc[6]);  acc[7]  = fmaf(hk, w1.w, acc[7]);
            acc[8]  = fmaf(hk, w2.x, acc[8]);  acc[9]  = fmaf(hk, w2.y, acc[9]);
            acc[10] = fmaf(hk, w2.z, acc[10]); acc[11] = fmaf(hk, w2.w, acc[11]);
            acc[12] = fmaf(hk, w3.x, acc[12]); acc[13] = fmaf(hk, w3.y, acc[13]);
            acc[14] = fmaf(hk, w3.z, acc[14]); acc[15] = fmaf(hk, w3.w, acc[15]);
        }
        unsigned pk[8];
        #pragma unroll
        for (int q = 0; q < 8; ++q)
            pk[q] = pk2bf(silu(acc[2*q] * INV_SQRT_RB),
                          silu(acc[2*q + 1] * INV_SQRT_RB));
        uint4 A; A.x = pk[0]; A.y = pk[1]; A.z = pk[2]; A.w = pk[3];
        uint4 B; B.x = pk[4]; B.y = pk[5]; B.z = pk[6]; B.w = pk[7];
        *(uint4*)&h0[erow][j0]     = A;
        *(uint4*)&h0[erow][j0 + 8] = B;
    }

    // ---- layer 2: h0 -> h1
    {
        bf16x8 a0 = *(const bf16x8*)&h0[erow][g4 * 8];
        bf16x8 a1 = *(const bf16x8*)&h0[erow][32 + g4 * 8];
        #pragma unroll
        for (int nt = 0; nt < 4; ++nt) {
            bf16x8 b0 = *(const bf16x8*)(W2p + ((nt * 2 + 0) * 64 + l) * 8);
            bf16x8 b1 = *(const bf16x8*)(W2p + ((nt * 2 + 1) * 64 + l) * 8);
            f32x4 c = {0.f, 0.f, 0.f, 0.f};
            c = __builtin_amdgcn_mfma_f32_16x16x32_bf16(a0, b0, c, 0, 0, 0);
            c = __builtin_amdgcn_mfma_f32_16x16x32_bf16(a1, b1, c, 0, 0, 0);
            #pragma unroll
            for (int r = 0; r < 4; ++r)
                h1[w * 16 + g4 * 4 + r][nt * 16 + r16] = f2bf(silu(c[r]));
        }
    }

    // ---- layer 3: h1 -> h0
    {
        bf16x8 a0 = *(const bf16x8*)&h1[erow][g4 * 8];
        bf16x8 a1 = *(const bf16x8*)&h1[erow][32 + g4 * 8];
        #pragma unroll
        for (int nt = 0; nt < 4; ++nt) {
            bf16x8 b0 = *(const bf16x8*)(W3p + ((nt * 2 + 0) * 64 + l) * 8);
            bf16x8 b1 = *(const bf16x8*)(W3p + ((nt * 2 + 1) * 64 + l) * 8);
            f32x4 c = {0.f, 0.f, 0.f, 0.f};
            c = __builtin_amdgcn_mfma_f32_16x16x32_bf16(a0, b0, c, 0, 0, 0);
            c = __builtin_amdgcn_mfma_f32_16x16x32_bf16(a1, b1, c, 0, 0, 0);
            #pragma unroll
            for (int r = 0; r < 4; ++r)
                h0[w * 16 + g4 * 4 + r][nt * 16 + r16] = f2bf(silu(c[r]));
        }
    }

    // ---- layer 4 (swapped operands) + LDS-staged coalesced stores ----
    // write phase: lane holds ch = 8*gidx + 4*h + g4 for edge w*16+r16
    // read  phase: lane l -> edge l>>2, ch pair (2*(l&3), 2*(l&3)+1) of group
    {
        bf16x8 ha0 = *(const bf16x8*)&h0[erow][g4 * 8];
        bf16x8 ha1 = *(const bf16x8*)&h0[erow][32 + g4 * 8];
        const int ebase = base + w * 16;
        const int er = l >> 2;                    // read-phase edge 0..15
        const int pr = l & 3;                     // read-phase ch-pair
        const bool vst = (ebase + er) < ne;
        unsigned short* twb = tpw16 + (size_t)(ebase + er) * 512;
        uint2 (*sw)[17] = stg[w];

        #pragma unroll 4
        for (int gidx = 0; gidx < 16; ++gidx) {
            #pragma unroll
            for (int h = 0; h < 2; ++h) {
                const int nt = gidx * 2 + h;
                bf16x8 w0 = *(const bf16x8*)(W4p + ((nt * 2 + 0) * 64 + l) * 8);
                bf16x8 w1 = *(const bf16x8*)(W4p + ((nt * 2 + 1) * 64 + l) * 8);
                f32x4 c = {0.f, 0.f, 0.f, 0.f};
                c = __builtin_amdgcn_mfma_f32_16x16x32_bf16(w0, ha0, c, 0, 0, 0);
                c = __builtin_amdgcn_mfma_f32_16x16x32_bf16(w1, ha1, c, 0, 0, 0);
                uint2 u;
                u.x = pk2bf(c[0], c[1]);
                u.y = pk2bf(c[2], c[3]);
                sw[h * 4 + g4][r16] = u;
            }
            // wave-internal: compiler inserts lgkmcnt before these reads
            uint2 a = sw[pr * 2][er];
            uint2 b = sw[pr * 2 + 1][er];
            if (vst) {
                uint4 v; v.x = a.x; v.y = a.y; v.z = b.x; v.w = b.y;
                *(uint4*)(twb + gidx * 32 + pr * 8) = v;
            }
        }
    }
}

// ---------------- K3: CSR gather per node (chunk-clipped) --------
// msg layout: [s0(128) | s1(128) | v m=0 (256) | m=1 (256) | m=2 (256)]
__global__ __launch_bounds__(128) void k_gather(
    const int*    __restrict__ row,
    const int*    __restrict__ snds,
    const float4* __restrict__ eas,
    const unsigned short* __restrict__ tpw16,
    const float*  __restrict__ s_up,
    const float*  __restrict__ v_up,
    float*        __restrict__ msg,
    int c0, int c1, int accum) {
    const int nidx = blockIdx.x;
    const int c = threadIdx.x;      // 128 threads, one channel each
    int beg = row[nidx];
    int end = row[nidx + 1];
    if (beg < c0) beg = c0;
    if (end > c1) end = c1;
    if (accum && beg >= end) return;

    float a0 = 0.f, a1 = 0.f, a2 = 0.f, a3 = 0.f,
          a4 = 0.f, a5 = 0.f, a6 = 0.f, a7 = 0.f;

    #pragma unroll 4
    for (int i = beg; i < end; ++i) {
        const int snd = snds[i];
        const float4 ea = eas[i];
        const float y0 = ea.x, y10 = ea.y, y11 = ea.z, y12 = ea.w;

        const uint2 u = *(const uint2*)(tpw16 + (size_t)(i - c0) * 512 + c * 4);
        const float t0 = bf2f(u.x & 0xffffu);
        const float t1 = bf2f(u.x >> 16);
        const float t2 = bf2f(u.y & 0xffffu);
        const float t3 = bf2f(u.y >> 16);
        const float se  = s_up[(size_t)snd * 128 + c];
        const float ve0 = v_up[(size_t)snd * 384 + 3 * c + 0];
        const float ve1 = v_up[(size_t)snd * 384 + 3 * c + 1];
        const float ve2 = v_up[(size_t)snd * 384 + 3 * c + 2];

        a0 = fmaf(C000 * t0 * y0, se, a0);
        const float dvy = ve0 * y10 + ve1 * y11 + ve2 * y12;
        a1 = fmaf(C110 * t3, dvy, a1);
        const float c011t = C011 * t1 * se;
        a2 = fmaf(c011t, y10, a2);
        a3 = fmaf(c011t, y11, a3);
        a4 = fmaf(c011t, y12, a4);
        const float c101t = C101 * t2 * y0;
        a5 = fmaf(c101t, ve0, a5);
        a6 = fmaf(c101t, ve1, a6);
        a7 = fmaf(c101t, ve2, a7);
    }

    float* m = msg + (size_t)nidx * 1024;
    if (accum) {
        m[c]             += a0;
        m[128 + c]       += a1;
        m[256 + c]       += a2;   // v plane m=0, k = c
        m[512 + c]       += a3;   // v plane m=1
        m[768 + c]       += a4;   // v plane m=2
        m[256 + 128 + c] += a5;   // v plane m=0, k = 128+c
        m[512 + 128 + c] += a6;
        m[768 + 128 + c] += a7;
    } else {
        m[c]             = a0;
        m[128 + c]       = a1;
        m[256 + c]       = a2;
        m[512 + c]       = a3;
        m[768 + c]       = a4;
        m[256 + 128 + c] = a5;
        m[512 + 128 + c] = a6;
        m[768 + 128 + c] = a7;
    }
}

// ---------------- K4: final node linear, MFMA, 8 waves/block ----------------
__global__ __launch_bounds__(512) void k_node_out(
    const float* __restrict__ msg,
    const short* __restrict__ Wlsp,
    const short* __restrict__ Wlvp,
    float*       __restrict__ out) {
    const int tid = threadIdx.x;
    const int l   = tid & 63;        // lane
    const int w   = tid >> 6;        // wave 0..7
    const int sec = w & 3;           // 0=s, 1..3=v planes
    const int nth = w >> 2;          // nt half: 0 or 1
    const int r16 = l & 15;
    const int g4  = l >> 4;
    const int n0  = blockIdx.x * 16;
    const float* mrow = msg + (size_t)(n0 + r16) * 1024 + sec * 256;

    bf16x8 a[8];
    #pragma unroll
    for (int kt = 0; kt < 8; ++kt) {
        const float* p = mrow + kt * 32 + g4 * 8;
        float4 x0 = *(const float4*)p;
        float4 x1 = *(const float4*)(p + 4);
        bf16x8 t;
        t[0] = f2bf(x0.x); t[1] = f2bf(x0.y); t[2] = f2bf(x0.z); t[3] = f2bf(x0.w);
        t[4] = f2bf(x1.x); t[5] = f2bf(x1.y); t[6] = f2bf(x1.z); t[7] = f2bf(x1.w);
        a[kt] = t;
    }
    const short* Wp = (sec == 0) ? Wlsp : Wlvp;
    #pragma unroll
    for (int ni = 0; ni < 4; ++ni) {
        const int nt = nth * 4 + ni;
        f32x4 c = {0.f, 0.f, 0.f, 0.f};
        #pragma unroll
        for (int kt = 0; kt < 8; ++kt) {
            bf16x8 b = *(const bf16x8*)(Wp + ((nt * 8 + kt) * 64 + l) * 8);
            c = __builtin_amdgcn_mfma_f32_16x16x32_bf16(a[kt], b, c, 0, 0, 0);
        }
        const int d = nt * 16 + r16;
        #pragma unroll
        for (int r = 0; r < 4; ++r) {
            const size_t n = n0 + g4 * 4 + r;
            if (sec == 0) out[n * 512 + d] = c[r];
            else          out[n * 512 + 128 + 3 * d + (sec - 1)] = c[r];
        }
    }
}

extern "C" void kernel_launch(void* const* d_in, const int* in_sizes, int n_in,
                              void* d_out, int out_size, void* d_ws, size_t ws_size,
                              hipStream_t stream) {
    const float* node_feats = (const float*)d_in[1];
    const float* edge_attrs = (const float*)d_in[2];
    const float* edge_feats = (const float*)d_in[3];
    const int*   edge_index = (const int*)d_in[4];
    const float* W_up_s = (const float*)d_in[5];
    const float* W_up_v = (const float*)d_in[6];
    const float* W_mlp1 = (const float*)d_in[7];
    const float* W_mlp2 = (const float*)d_in[8];
    const float* W_mlp3 = (const float*)d_in[9];
    const float* W_mlp4 = (const float*)d_in[10];
    const float* W_lin_s = (const float*)d_in[11];
    const float* W_lin_v = (const float*)d_in[12];

    float* ws     = (float*)d_ws;
    float* s_up   = ws + S_UP_OFF;
    float* v_up   = ws + V_UP_OFF;
    float* msg    = ws + MSG_OFF;
    short* W2p    = (short*)(ws + WP_OFF);   // 4096 shorts
    short* W3p    = W2p + 4096;              // 4096
    short* W4p    = W3p + 4096;              // 32768
    short* Wlsp   = W4p + 32768;             // 32768
    short* Wlvp   = Wlsp + 32768;            // 32768
    int*   row    = (int*)(ws + ROW_OFF);
    int*   elist  = (int*)(ws + ELIST_OFF);
    int*   snds   = (int*)(ws + SNDS_OFF);
    float4* eas   = (float4*)(ws + EAS_OFF);
    unsigned short* tpw16 = (unsigned short*)(ws + TPW_OFF);
    int*   cnt    = (int*)msg;
    int*   cursor = cnt + N_NODES;
    float* out_f  = (float*)d_out;

    // adaptive chunking from actual ws_size (deterministic across calls)
    size_t total_f = ws_size / 4;
    if (total_f > MAX_TOTAL_F) total_f = MAX_TOTAL_F;
    size_t cap_f = (total_f > TPW_OFF) ? (total_f - TPW_OFF) : 0;
    long long ce = (long long)(cap_f / 256);   // 512 bf16 = 256 floats per edge
    ce &= ~63LL;
    if (ce < 64) ce = 64;
    if (ce > N_EDGES) ce = N_EDGES;
    const int chunkE = (int)ce;                 // = N_EDGES (single chunk) at ~390MB ws
    const int nch = (N_EDGES + chunkE - 1) / chunkE;

    (void)hipMemsetAsync(cnt, 0, 2 * N_NODES * sizeof(int), stream);
    k_pack<<<416, 256, 0, stream>>>(W_mlp2, W_mlp3, W_mlp4, W_lin_s, W_lin_v,
                                    W2p, W3p, W4p, Wlsp, Wlvp);
    k_node_up<<<N_NODES / NPB, 128, 0, stream>>>(node_feats, W_up_s, W_up_v, s_up, v_up);
    k_hist<<<N_EDGES / 256, 256, 0, stream>>>(edge_index, cnt);
    k_scan<<<1, 256, 0, stream>>>(cnt, row, cursor);
    k_scatter<<<N_EDGES / 256, 256, 0, stream>>>(edge_index, cursor, edge_attrs,
                                                 elist, snds, eas);

    for (int ch = 0; ch < nch; ++ch) {
        const int c0 = ch * chunkE;
        const int c1 = (c0 + chunkE < N_EDGES) ? c0 + chunkE : N_EDGES;
        const int ne = c1 - c0;
        k_edge_mfma<<<(ne + 63) / 64, 256, 0, stream>>>(
            edge_feats, W_mlp1, W2p, W3p, W4p, elist, c0, ne, tpw16);
        k_gather<<<N_NODES, 128, 0, stream>>>(
            row, snds, eas, tpw16, s_up, v_up, msg, c0, c1, ch == 0 ? 0 : 1);
    }
    k_node_out<<<625, 512, 0, stream>>>(msg, Wlsp, Wlvp, out_f);
}